// Round 4
// baseline (880.894 us; speedup 1.0000x reference)
//
#include <hip/hip_runtime.h>
#include <math.h>

// Problem: B=32, C=192, H=W=32, CH=8, stride=2 -> FEAT=2048, N=C*C=36864
// Pipeline: conv(+relu) -> linear -> per-batch LU (partial pivot) ->
//           weight = mats + P*(L*diag(d)) in-place -> out = weight @ inp ; logdet.

#define NFEAT 2048
#define NN    36864

// ---------------- Stage 1: conv partials (c-sliced) ----------------
// grid 128 = b*4+cs, block 256 (=16x16 output pixels). hpart[cs][b][ch*256+pix]
__global__ __launch_bounds__(256) void conv_kernel(const float* __restrict__ w,
                                                   const float* __restrict__ cw,
                                                   float* __restrict__ hpart) {
  int blk = blockIdx.x;
  int b = blk >> 2, cs = blk & 3;
  int tid = threadIdx.x;
  int oy = tid >> 4, ox = tid & 15;
  __shared__ float wlds[8 * 48 * 9];
  for (int idx = tid; idx < 8 * 48 * 9; idx += 256) {
    int ch = idx / 432, rem = idx - ch * 432;
    int c = rem / 9, kk = rem - c * 9;
    wlds[idx] = cw[ch * 1728 + (cs * 48 + c) * 9 + kk];
  }
  __syncthreads();
  float acc[8];
#pragma unroll
  for (int ch = 0; ch < 8; ++ch) acc[ch] = 0.f;
  const float* img0 = w + (((size_t)b * 192 + cs * 48) << 10);
  for (int c = 0; c < 48; ++c) {
    const float* img = img0 + ((size_t)c << 10);
    float iv[9];
#pragma unroll
    for (int ky = 0; ky < 3; ++ky)
#pragma unroll
      for (int kx = 0; kx < 3; ++kx) {
        int iy = 2 * oy - 1 + ky, ix = 2 * ox - 1 + kx;
        bool ok = (iy >= 0) & (iy < 32) & (ix >= 0) & (ix < 32);
        iv[ky * 3 + kx] = ok ? img[iy * 32 + ix] : 0.f;
      }
#pragma unroll
    for (int ch = 0; ch < 8; ++ch) {
      const float* wp = &wlds[(ch * 48 + c) * 9];
      float s = acc[ch];
#pragma unroll
      for (int t = 0; t < 9; ++t) s = fmaf(iv[t], wp[t], s);
      acc[ch] = s;
    }
  }
  size_t base = ((size_t)(cs * 32 + b) << 11) + tid;
#pragma unroll
  for (int ch = 0; ch < 8; ++ch) hpart[base + (ch << 8)] = acc[ch];
}

// ---------------- Stage 2: reduce partials + bias + relu -> h_t[k][b] ----------------
__global__ __launch_bounds__(256) void hreduce_kernel(const float* __restrict__ hpart,
                                                      const float* __restrict__ cb,
                                                      float* __restrict__ h_t) {
  int g = blockIdx.x * 256 + threadIdx.x;   // 0..65535
  int k = g & 2047, b = g >> 11;
  float s = 0.f;
#pragma unroll
  for (int cs = 0; cs < 4; ++cs) s += hpart[(((size_t)(cs * 32 + b)) << 11) + k];
  s += cb[k >> 8];
  s = fmaxf(s, 0.f);
  h_t[((size_t)k << 5) + b] = s;
}

// ---------------- Stage 3: linear  mats[b][n] = sum_k h[b][k]*lw[n][k] + lb[n] ------
// grid 576 (64 n per block); 4 waves split K into quarters of 512; lane <-> n.
__global__ __launch_bounds__(256) void linear_kernel(const float* __restrict__ h_t,
                                                     const float* __restrict__ lw,
                                                     const float* __restrict__ lb,
                                                     float* __restrict__ mats) {
  __shared__ float smem[4 * 64 * 68];   // W staging; aliased as accbuf[4][64][33]
  int tid = threadIdx.x;
  int l = tid & 63;
  int wq = __builtin_amdgcn_readfirstlane(tid >> 6);
  int n0 = blockIdx.x << 6;
  int kbase = wq << 9;
  float* wl = smem + wq * (64 * 68);
  float acc[32];
#pragma unroll
  for (int i = 0; i < 32; ++i) acc[i] = 0.f;
  for (int kc = 0; kc < 8; ++kc) {
    int koff = kbase + (kc << 6);
    // stage 64 rows x 64 k (coalesced float4), padded stride 68
#pragma unroll
    for (int j = 0; j < 16; ++j) {
      int f = l + (j << 6);
      int row = f >> 4, c4 = (f & 15) << 2;
      float4 v = *(const float4*)(lw + (size_t)(n0 + row) * 2048 + koff + c4);
      *(float4*)(wl + row * 68 + c4) = v;
    }
#pragma unroll 2
    for (int kk = 0; kk < 64; ++kk) {
      float wv = wl[l * 68 + kk];
      const float4* hp = (const float4*)(h_t + ((size_t)(koff + kk) << 5));
#pragma unroll
      for (int q = 0; q < 8; ++q) {
        float4 hv = hp[q];
        acc[4 * q + 0] = fmaf(hv.x, wv, acc[4 * q + 0]);
        acc[4 * q + 1] = fmaf(hv.y, wv, acc[4 * q + 1]);
        acc[4 * q + 2] = fmaf(hv.z, wv, acc[4 * q + 2]);
        acc[4 * q + 3] = fmaf(hv.w, wv, acc[4 * q + 3]);
      }
    }
  }
  __syncthreads();                       // all waves done with W staging regions
  float* accbuf = smem;                  // [4][64][33]
  float* mine = accbuf + (wq * 64 + l) * 33;
#pragma unroll
  for (int i = 0; i < 32; ++i) mine[i] = acc[i];
  __syncthreads();
#pragma unroll
  for (int r = 0; r < 8; ++r) {
    int q = r * 256 + tid;               // 0..2047
    int nsub = q & 63, b = q >> 6;
    float s = accbuf[(0 * 64 + nsub) * 33 + b] + accbuf[(1 * 64 + nsub) * 33 + b] +
              accbuf[(2 * 64 + nsub) * 33 + b] + accbuf[(3 * 64 + nsub) * 33 + b];
    s += lb[n0 + nsub];
    mats[(size_t)b * NN + n0 + nsub] = s;
  }
}

// ---------------- Stage 4: per-batch LU + in-place weight reconstruction ----------
// 32 blocks x 1024 threads. Thread (g_r=tid&31, g_c=tid>>5) owns rows r=g_r+32*rr
// (rr 0..5) x cols c=g_c+32*cc (cc 0..5) = 36 floats held as SIX 6-float arrays
// (a0..a5, X-macro static dispatch). R2/R3 post-mortem: 72/144-float allocas are
// NOT promoted to VGPRs (size threshold; VGPR_Count=64 with scratch traffic);
// proven-promoted arrays in this binary are <=32 elements, so keep each <=6.
// Arithmetic is op-for-op identical to R2/R3 (same pivot rule, same fmaf order).
__global__ __launch_bounds__(1024, 1) void lu_kernel(float* __restrict__ A0,
                                                     const float* __restrict__ ssign,
                                                     float* __restrict__ ssum) {
  int b = blockIdx.x;
  float* __restrict__ A = A0 + (size_t)b * NN;
  int tid = threadIdx.x;
  int g_r = tid & 31, g_c = tid >> 5;   // both 0..31
  __shared__ float bufK[192], bufP[192], mbuf[192], diagU[192], dval[192];
  __shared__ int perm[192];
  __shared__ int pivSh;
  for (int i = tid; i < 192; i += 1024) perm[i] = i;
  float a0[6], a1[6], a2[6], a3[6], a4[6], a5[6];
#define LU_ROWS(OP) OP(0, a0) OP(1, a1) OP(2, a2) OP(3, a3) OP(4, a4) OP(5, a5)

#define LU_LOAD(RR, AR)                                                        \
  _Pragma("unroll") for (int cc = 0; cc < 6; ++cc)                             \
      AR[cc] = A[(g_r + 32 * RR) * 192 + g_c + 32 * cc];
  LU_ROWS(LU_LOAD)
#undef LU_LOAD
  __syncthreads();

  for (int k = 0; k < 192; ++k) {
    const int km = k & 31, kd = k >> 5;
    // phase 1: pivot candidates (col-k owners = 32 consecutive tids = half-wave)
    float bv = -1.f;
    int br = 0x7fffff;
    if (g_c == km) {
#define LU_PIV(RR, AR)                                                         \
  _Pragma("unroll") for (int cc = 0; cc < 6; ++cc) if (cc == kd) {             \
    int r = g_r + 32 * RR;                                                     \
    float v = fabsf(AR[cc]);                                                   \
    if (r >= k && v > bv) { bv = v; br = r; }                                  \
  }
      LU_ROWS(LU_PIV)
#undef LU_PIV
    }
#pragma unroll
    for (int mask = 1; mask <= 16; mask <<= 1) {
      float ov = __shfl_xor(bv, mask, 64);
      int obr = __shfl_xor(br, mask, 64);
      if (ov > bv || (ov == bv && obr < br)) { bv = ov; br = obr; }
    }
    if (g_c == km && g_r == 0) pivSh = br;
    // row-k extraction -> bufK
    if (g_r == km) {
#define LU_EXTK(RR, AR)                                                        \
  if (RR == kd) {                                                              \
    _Pragma("unroll") for (int cc = 0; cc < 6; ++cc)                           \
        bufK[g_c + 32 * cc] = AR[cc];                                          \
  }
      LU_ROWS(LU_EXTK)
#undef LU_EXTK
    }
    __syncthreads();  // bar1
    const int p = pivSh;
    const int pm = p & 31, pd = p >> 5;
    if (g_r == pm) {
#define LU_EXTP(RR, AR)                                                        \
  if (RR == pd) {                                                              \
    _Pragma("unroll") for (int cc = 0; cc < 6; ++cc)                           \
        bufP[g_c + 32 * cc] = AR[cc];                                          \
  }
      LU_ROWS(LU_EXTP)
#undef LU_EXTP
    }
    __syncthreads();  // bar2
    if (tid == 0) {
      int t = perm[k]; perm[k] = perm[p]; perm[p] = t;
      diagU[k] = bufP[k];
    }
    if (p != k) {
      if (g_r == km) {
#define LU_SWK(RR, AR)                                                         \
  if (RR == kd) {                                                              \
    _Pragma("unroll") for (int cc = 0; cc < 6; ++cc)                           \
        AR[cc] = bufP[g_c + 32 * cc];                                          \
  }
        LU_ROWS(LU_SWK)
#undef LU_SWK
      }
      if (g_r == pm) {
#define LU_SWP(RR, AR)                                                         \
  if (RR == pd) {                                                              \
    _Pragma("unroll") for (int cc = 0; cc < 6; ++cc)                           \
        AR[cc] = bufK[g_c + 32 * cc];                                          \
  }
        LU_ROWS(LU_SWP)
#undef LU_SWP
      }
    }
    if (g_c == km) {                    // multipliers (LAPACK-style reciprocal)
      float rp = 1.0f / bufP[k];
#define LU_MUL(RR, AR)                                                         \
  _Pragma("unroll") for (int cc = 0; cc < 6; ++cc) if (cc == kd) {             \
    int r = g_r + 32 * RR;                                                     \
    if (r > k) {                                                               \
      float m = AR[cc] * rp;                                                   \
      AR[cc] = m;                                                              \
      mbuf[r] = m;                                                             \
    } else                                                                     \
      mbuf[r] = 0.f;                                                           \
  }
      LU_ROWS(LU_MUL)
#undef LU_MUL
    }
    __syncthreads();  // bar3
    // phase 4: rank-1 trailing update, branch-free via zero-masked mbuf/uv
    float uv[6];
#pragma unroll
    for (int cc = 0; cc < 6; ++cc) {
      int c = g_c + 32 * cc;
      uv[cc] = (c > k) ? bufP[c] : 0.f;
    }
#define LU_UPD(RR, AR)                                                         \
  {                                                                            \
    float m = mbuf[g_r + 32 * RR];                                             \
    _Pragma("unroll") for (int cc = 0; cc < 6; ++cc)                           \
        AR[cc] = fmaf(-m, uv[cc], AR[cc]);                                     \
  }
    LU_ROWS(LU_UPD)
#undef LU_UPD
  }
  // epilogue: logdet partial + weight = A + P*(L*diag(d)) in place
  if (tid == 0) {
    float s = 0.f;
    for (int i = 0; i < 192; ++i) s += diagU[i];
    ssum[b] = s;
  }
  for (int i = tid; i < 192; i += 1024) dval[i] = ssign[i] * expf(diagU[i]) - diagU[i];
  __syncthreads();
#define LU_EPI(RR, AR)                                                         \
  {                                                                            \
    int i = g_r + 32 * RR;                                                     \
    int pi = perm[i];                                                          \
    float di = dval[i];                                                        \
    float* __restrict__ row = A + (size_t)pi * 192;                            \
    _Pragma("unroll") for (int cc = 0; cc < 6; ++cc) {                         \
      int j = g_c + 32 * cc;                                                   \
      if (j < i)                                                               \
        row[j] += AR[cc] * dval[j];                                            \
      else if (j == i)                                                         \
        row[j] += di;                                                          \
    }                                                                          \
  }
  LU_ROWS(LU_EPI)
#undef LU_EPI
#undef LU_ROWS
}

// ---------------- Stage 5: out[b] = weight[b] @ inp[b]  (+ logdet write) ----------
// grid 768 = b*24 + it*8 + jt ; tile 64(i) x 128(hw), BK=32, thread 8x4.
__global__ __launch_bounds__(256) void out_kernel(const float* __restrict__ wt,
                                                  const float* __restrict__ inp,
                                                  const float* __restrict__ ssum,
                                                  float* __restrict__ out) {
  int blk = blockIdx.x;
  int b = blk / 24, rem = blk % 24;
  int it = rem >> 3, jt = rem & 7;
  int i0 = it << 6, hw0 = jt << 7;
  int tid = threadIdx.x;
  int tx = tid & 31, ty = tid >> 5;
  __shared__ float wlds[64 * 36];
  __shared__ float xlds[32 * 128];
  const float* wb = wt + (size_t)b * NN;
  const float* xb = inp + (((size_t)b * 192) << 10);
  float acc[8][4];
#pragma unroll
  for (int r = 0; r < 8; ++r)
#pragma unroll
    for (int c = 0; c < 4; ++c) acc[r][c] = 0.f;
  for (int kc = 0; kc < 6; ++kc) {
    __syncthreads();
#pragma unroll
    for (int j = 0; j < 2; ++j) {
      int f4 = tid + (j << 8);
      int row = f4 >> 3, c4 = (f4 & 7) << 2;
      float4 v = *(const float4*)(wb + (size_t)(i0 + row) * 192 + (kc << 5) + c4);
      *(float4*)(wlds + row * 36 + c4) = v;
    }
#pragma unroll
    for (int j = 0; j < 4; ++j) {
      int f4 = tid + (j << 8);
      int row = f4 >> 5, c4 = (f4 & 31) << 2;
      float4 v = *(const float4*)(xb + (((size_t)(kc << 5) + row) << 10) + hw0 + c4);
      *(float4*)(xlds + (row << 7) + c4) = v;
    }
    __syncthreads();
#pragma unroll 4
    for (int k = 0; k < 32; ++k) {
      float4 xv = *(const float4*)(xlds + (k << 7) + (tx << 2));
      float wr[8];
#pragma unroll
      for (int r = 0; r < 8; ++r) wr[r] = wlds[(ty * 8 + r) * 36 + k];
#pragma unroll
      for (int r = 0; r < 8; ++r) {
        acc[r][0] = fmaf(wr[r], xv.x, acc[r][0]);
        acc[r][1] = fmaf(wr[r], xv.y, acc[r][1]);
        acc[r][2] = fmaf(wr[r], xv.z, acc[r][2]);
        acc[r][3] = fmaf(wr[r], xv.w, acc[r][3]);
      }
    }
  }
  float* ob = out + (((size_t)b * 192 + i0 + ty * 8) << 10) + hw0 + (tx << 2);
#pragma unroll
  for (int r = 0; r < 8; ++r) {
    float4 v = make_float4(acc[r][0], acc[r][1], acc[r][2], acc[r][3]);
    *(float4*)(ob + ((size_t)r << 10)) = v;
  }
  if (blk == 0 && tid == 0) {
    float s = 0.f;
    for (int i = 0; i < 32; ++i) s += ssum[i];
    out[6291456] = 32.f * s;   // H*W * mean over batch of sum(s)
  }
}

extern "C" void kernel_launch(void* const* d_in, const int* in_sizes, int n_in,
                              void* d_out, int out_size, void* d_ws, size_t ws_size,
                              hipStream_t stream) {
  const float* inp = (const float*)d_in[0];
  const float* wlo = (const float*)d_in[1];
  const float* cw  = (const float*)d_in[2];
  const float* cb  = (const float*)d_in[3];
  const float* lw  = (const float*)d_in[4];
  const float* lb  = (const float*)d_in[5];
  const float* ss  = (const float*)d_in[6];
  float* out = (float*)d_out;
  float* ws = (float*)d_ws;
  // ws layout (floats): hpart 262144 | h_t 65536 | mats 1179648 | ssum 32  (~6 MB)
  float* hpart = ws;
  float* h_t   = ws + 262144;
  float* mats  = ws + 327680;
  float* ssum  = ws + 1507328;
  hipLaunchKernelGGL(conv_kernel,    dim3(128), dim3(256),  0, stream, wlo, cw, hpart);
  hipLaunchKernelGGL(hreduce_kernel, dim3(256), dim3(256),  0, stream, hpart, cb, h_t);
  hipLaunchKernelGGL(linear_kernel,  dim3(576), dim3(256),  0, stream, h_t, lw, lb, mats);
  hipLaunchKernelGGL(lu_kernel,      dim3(32),  dim3(1024), 0, stream, mats, ss, ssum);
  hipLaunchKernelGGL(out_kernel,     dim3(768), dim3(256),  0, stream, mats, inp, ssum, out);
}

// Round 5
// 687.731 us; speedup vs baseline: 1.2809x; 1.2809x over previous
//
#include <hip/hip_runtime.h>
#include <math.h>

// Problem: B=32, C=192, H=W=32, CH=8, stride=2 -> FEAT=2048, N=C*C=36864
// Pipeline: conv(+relu) -> linear -> per-batch LU (partial pivot) ->
//           weight = mats + P*(L*diag(d)) in-place -> out = weight @ inp ; logdet.

#define NFEAT 2048
#define NN    36864

// ---------------- Stage 1: conv partials (c-sliced) ----------------
// grid 128 = b*4+cs, block 256 (=16x16 output pixels). hpart[cs][b][ch*256+pix]
__global__ __launch_bounds__(256) void conv_kernel(const float* __restrict__ w,
                                                   const float* __restrict__ cw,
                                                   float* __restrict__ hpart) {
  int blk = blockIdx.x;
  int b = blk >> 2, cs = blk & 3;
  int tid = threadIdx.x;
  int oy = tid >> 4, ox = tid & 15;
  __shared__ float wlds[8 * 48 * 9];
  for (int idx = tid; idx < 8 * 48 * 9; idx += 256) {
    int ch = idx / 432, rem = idx - ch * 432;
    int c = rem / 9, kk = rem - c * 9;
    wlds[idx] = cw[ch * 1728 + (cs * 48 + c) * 9 + kk];
  }
  __syncthreads();
  float acc[8];
#pragma unroll
  for (int ch = 0; ch < 8; ++ch) acc[ch] = 0.f;
  const float* img0 = w + (((size_t)b * 192 + cs * 48) << 10);
  for (int c = 0; c < 48; ++c) {
    const float* img = img0 + ((size_t)c << 10);
    float iv[9];
#pragma unroll
    for (int ky = 0; ky < 3; ++ky)
#pragma unroll
      for (int kx = 0; kx < 3; ++kx) {
        int iy = 2 * oy - 1 + ky, ix = 2 * ox - 1 + kx;
        bool ok = (iy >= 0) & (iy < 32) & (ix >= 0) & (ix < 32);
        iv[ky * 3 + kx] = ok ? img[iy * 32 + ix] : 0.f;
      }
#pragma unroll
    for (int ch = 0; ch < 8; ++ch) {
      const float* wp = &wlds[(ch * 48 + c) * 9];
      float s = acc[ch];
#pragma unroll
      for (int t = 0; t < 9; ++t) s = fmaf(iv[t], wp[t], s);
      acc[ch] = s;
    }
  }
  size_t base = ((size_t)(cs * 32 + b) << 11) + tid;
#pragma unroll
  for (int ch = 0; ch < 8; ++ch) hpart[base + (ch << 8)] = acc[ch];
}

// ---------------- Stage 2: reduce partials + bias + relu -> h_t[k][b] ----------------
__global__ __launch_bounds__(256) void hreduce_kernel(const float* __restrict__ hpart,
                                                      const float* __restrict__ cb,
                                                      float* __restrict__ h_t) {
  int g = blockIdx.x * 256 + threadIdx.x;   // 0..65535
  int k = g & 2047, b = g >> 11;
  float s = 0.f;
#pragma unroll
  for (int cs = 0; cs < 4; ++cs) s += hpart[(((size_t)(cs * 32 + b)) << 11) + k];
  s += cb[k >> 8];
  s = fmaxf(s, 0.f);
  h_t[((size_t)k << 5) + b] = s;
}

// ---------------- Stage 3: linear  mats[b][n] = sum_k h[b][k]*lw[n][k] + lb[n] ------
// grid 576 (64 n per block); 4 waves split K into quarters of 512; lane <-> n.
__global__ __launch_bounds__(256) void linear_kernel(const float* __restrict__ h_t,
                                                     const float* __restrict__ lw,
                                                     const float* __restrict__ lb,
                                                     float* __restrict__ mats) {
  __shared__ float smem[4 * 64 * 68];   // W staging; aliased as accbuf[4][64][33]
  int tid = threadIdx.x;
  int l = tid & 63;
  int wq = __builtin_amdgcn_readfirstlane(tid >> 6);
  int n0 = blockIdx.x << 6;
  int kbase = wq << 9;
  float* wl = smem + wq * (64 * 68);
  float acc[32];
#pragma unroll
  for (int i = 0; i < 32; ++i) acc[i] = 0.f;
  for (int kc = 0; kc < 8; ++kc) {
    int koff = kbase + (kc << 6);
    // stage 64 rows x 64 k (coalesced float4), padded stride 68
#pragma unroll
    for (int j = 0; j < 16; ++j) {
      int f = l + (j << 6);
      int row = f >> 4, c4 = (f & 15) << 2;
      float4 v = *(const float4*)(lw + (size_t)(n0 + row) * 2048 + koff + c4);
      *(float4*)(wl + row * 68 + c4) = v;
    }
#pragma unroll 2
    for (int kk = 0; kk < 64; ++kk) {
      float wv = wl[l * 68 + kk];
      const float4* hp = (const float4*)(h_t + ((size_t)(koff + kk) << 5));
#pragma unroll
      for (int q = 0; q < 8; ++q) {
        float4 hv = hp[q];
        acc[4 * q + 0] = fmaf(hv.x, wv, acc[4 * q + 0]);
        acc[4 * q + 1] = fmaf(hv.y, wv, acc[4 * q + 1]);
        acc[4 * q + 2] = fmaf(hv.z, wv, acc[4 * q + 2]);
        acc[4 * q + 3] = fmaf(hv.w, wv, acc[4 * q + 3]);
      }
    }
  }
  __syncthreads();                       // all waves done with W staging regions
  float* accbuf = smem;                  // [4][64][33]
  float* mine = accbuf + (wq * 64 + l) * 33;
#pragma unroll
  for (int i = 0; i < 32; ++i) mine[i] = acc[i];
  __syncthreads();
#pragma unroll
  for (int r = 0; r < 8; ++r) {
    int q = r * 256 + tid;               // 0..2047
    int nsub = q & 63, b = q >> 6;
    float s = accbuf[(0 * 64 + nsub) * 33 + b] + accbuf[(1 * 64 + nsub) * 33 + b] +
              accbuf[(2 * 64 + nsub) * 33 + b] + accbuf[(3 * 64 + nsub) * 33 + b];
    s += lb[n0 + nsub];
    mats[(size_t)b * NN + n0 + nsub] = s;
  }
}

// ---------------- Stage 4: per-batch LU, LDS-resident ----------
// R2-R4 post-mortem: per-thread register tiles are never promoted (VGPR 108/64/40
// with scratch traffic) -> keep the whole matrix in LDS instead (147KB < 160KB).
// 32 blocks x 768 threads (1 block/CU). Row stride 49 float4 (16B-aligned rows).
// Logical->physical rowmap instead of physical swaps: 2 barriers/iteration.
// Pivot rule (first max, ascending logical rows) identical to R2-R4 (passed).
__global__ __launch_bounds__(768, 1) void lu_kernel(float* __restrict__ A0,
                                                    const float* __restrict__ ssign,
                                                    float* __restrict__ ssum) {
  __shared__ float4 As4[192 * 49];     // 150528 B
  __shared__ int rowmap[192];
  __shared__ float diagU[192];
  __shared__ float4 dval4[48];
  __shared__ float shRecip;
  __shared__ int shUrow;
  float* As = (float*)As4;
  float* dvalf = (float*)dval4;
  int b = blockIdx.x;
  int tid = threadIdx.x;
  float* __restrict__ A = A0 + (size_t)b * NN;

  // load A -> LDS (coalesced float4; 9216 chunks / 768 threads = 12 each)
#pragma unroll
  for (int j = 0; j < 12; ++j) {
    int chunk = tid + 768 * j;
    int row = chunk / 48, q = chunk - row * 48;
    As4[row * 49 + q] = *(const float4*)(A + row * 192 + 4 * q);
  }
  for (int i = tid; i < 192; i += 768) rowmap[i] = i;
  __syncthreads();

  const int r = tid >> 2;       // logical row this thread serves in update phase
  const int tq = tid & 3;       // chunk residue (owns chunks q = tq+4j)

  for (int k = 0; k < 192; ++k) {
    // ---- phase 1: pivot scan over col k, logical rows >= k (wave 0 only) ----
    if (tid < 64) {
      float bv = -1.f;
      int br = 0x7fffffff;
#pragma unroll
      for (int j = 0; j < 3; ++j) {
        int rr = k + tid + 64 * j;
        if (rr < 192) {
          int ph = rowmap[rr];
          float v = fabsf(As[ph * 196 + k]);
          if (v > bv) { bv = v; br = rr; }   // ascending -> first max
        }
      }
#pragma unroll
      for (int mask = 1; mask <= 32; mask <<= 1) {
        float ov = __shfl_xor(bv, mask, 64);
        int obr = __shfl_xor(br, mask, 64);
        if (ov > bv || (ov == bv && obr < br)) { bv = ov; br = obr; }
      }
      if (tid == 0) {
        int pl = br;
        int rk = rowmap[k], rp = rowmap[pl];
        rowmap[k] = rp;
        rowmap[pl] = rk;
        float piv = As[rp * 196 + k];
        diagU[k] = piv;
        shRecip = 1.0f / piv;
        shUrow = rp;
      }
    }
    __syncthreads();  // bar1: rowmap/recip/urow visible
    // ---- phase 2: scale col k + rank-1 update, rows r > k ----
    if (r > k) {
      int phys = rowmap[r];
      int urow = shUrow;
      float m = As[phys * 196 + k] * shRecip;   // read before any col-k write
      float4* Ar = As4 + phys * 49;             // (same-wave lockstep makes this safe)
      const float4* Ur = As4 + urow * 49;
      int q0 = k >> 2;
      for (int j = 0; j < 12; ++j) {
        int q = tq + 4 * j;
        if (q < q0) continue;
        float4 a4 = Ar[q];
        float4 u4 = Ur[q];
        if (q == q0) {                          // boundary chunk: per-element
          int c0 = 4 * q;
          a4.x = (c0 + 0 < k) ? a4.x : ((c0 + 0 == k) ? m : fmaf(-m, u4.x, a4.x));
          a4.y = (c0 + 1 < k) ? a4.y : ((c0 + 1 == k) ? m : fmaf(-m, u4.y, a4.y));
          a4.z = (c0 + 2 < k) ? a4.z : ((c0 + 2 == k) ? m : fmaf(-m, u4.z, a4.z));
          a4.w = (c0 + 3 < k) ? a4.w : ((c0 + 3 == k) ? m : fmaf(-m, u4.w, a4.w));
        } else {
          a4.x = fmaf(-m, u4.x, a4.x);
          a4.y = fmaf(-m, u4.y, a4.y);
          a4.z = fmaf(-m, u4.z, a4.z);
          a4.w = fmaf(-m, u4.w, a4.w);
        }
        Ar[q] = a4;
      }
    }
    __syncthreads();  // bar2: updated trailing matrix visible to next pivot scan
  }

  // ---- epilogue: logdet partial, dval, weight = mats + P*(L*diag(d)) ----
  if (tid == 0) {
    float s = 0.f;
    for (int i = 0; i < 192; ++i) s += diagU[i];
    ssum[b] = s;
  }
  if (tid < 192) dvalf[tid] = ssign[tid] * expf(diagU[tid]) - diagU[tid];
  __syncthreads();
  {
    int i = r;
    int phys = rowmap[r];
    float di = dvalf[i];
    float* __restrict__ G = A + (size_t)phys * 192;   // output row = original row phys
    int qi = i >> 2;
    for (int j = 0; j < 12; ++j) {
      int q = tq + 4 * j;
      if (q > qi) continue;
      float4 g4 = *(float4*)(G + 4 * q);
      float4 a4 = As4[phys * 49 + q];
      float4 d4 = dval4[q];
      if (q == qi) {                              // boundary chunk: per-element
        int c0 = 4 * q;
        g4.x = (c0 + 0 < i) ? g4.x + a4.x * d4.x : ((c0 + 0 == i) ? g4.x + di : g4.x);
        g4.y = (c0 + 1 < i) ? g4.y + a4.y * d4.y : ((c0 + 1 == i) ? g4.y + di : g4.y);
        g4.z = (c0 + 2 < i) ? g4.z + a4.z * d4.z : ((c0 + 2 == i) ? g4.z + di : g4.z);
        g4.w = (c0 + 3 < i) ? g4.w + a4.w * d4.w : ((c0 + 3 == i) ? g4.w + di : g4.w);
      } else {                                    // full chunk: all cols < i
        g4.x += a4.x * d4.x;
        g4.y += a4.y * d4.y;
        g4.z += a4.z * d4.z;
        g4.w += a4.w * d4.w;
      }
      *(float4*)(G + 4 * q) = g4;
    }
  }
}

// ---------------- Stage 5: out[b] = weight[b] @ inp[b]  (+ logdet write) ----------
// grid 768 = b*24 + it*8 + jt ; tile 64(i) x 128(hw), BK=32, thread 8x4.
__global__ __launch_bounds__(256) void out_kernel(const float* __restrict__ wt,
                                                  const float* __restrict__ inp,
                                                  const float* __restrict__ ssum,
                                                  float* __restrict__ out) {
  int blk = blockIdx.x;
  int b = blk / 24, rem = blk % 24;
  int it = rem >> 3, jt = rem & 7;
  int i0 = it << 6, hw0 = jt << 7;
  int tid = threadIdx.x;
  int tx = tid & 31, ty = tid >> 5;
  __shared__ float wlds[64 * 36];
  __shared__ float xlds[32 * 128];
  const float* wb = wt + (size_t)b * NN;
  const float* xb = inp + (((size_t)b * 192) << 10);
  float acc[8][4];
#pragma unroll
  for (int r = 0; r < 8; ++r)
#pragma unroll
    for (int c = 0; c < 4; ++c) acc[r][c] = 0.f;
  for (int kc = 0; kc < 6; ++kc) {
    __syncthreads();
#pragma unroll
    for (int j = 0; j < 2; ++j) {
      int f4 = tid + (j << 8);
      int row = f4 >> 3, c4 = (f4 & 7) << 2;
      float4 v = *(const float4*)(wb + (size_t)(i0 + row) * 192 + (kc << 5) + c4);
      *(float4*)(wlds + row * 36 + c4) = v;
    }
#pragma unroll
    for (int j = 0; j < 4; ++j) {
      int f4 = tid + (j << 8);
      int row = f4 >> 5, c4 = (f4 & 31) << 2;
      float4 v = *(const float4*)(xb + (((size_t)(kc << 5) + row) << 10) + hw0 + c4);
      *(float4*)(xlds + (row << 7) + c4) = v;
    }
    __syncthreads();
#pragma unroll 4
    for (int k = 0; k < 32; ++k) {
      float4 xv = *(const float4*)(xlds + (k << 7) + (tx << 2));
      float wr[8];
#pragma unroll
      for (int r = 0; r < 8; ++r) wr[r] = wlds[(ty * 8 + r) * 36 + k];
#pragma unroll
      for (int r = 0; r < 8; ++r) {
        acc[r][0] = fmaf(wr[r], xv.x, acc[r][0]);
        acc[r][1] = fmaf(wr[r], xv.y, acc[r][1]);
        acc[r][2] = fmaf(wr[r], xv.z, acc[r][2]);
        acc[r][3] = fmaf(wr[r], xv.w, acc[r][3]);
      }
    }
  }
  float* ob = out + (((size_t)b * 192 + i0 + ty * 8) << 10) + hw0 + (tx << 2);
#pragma unroll
  for (int r = 0; r < 8; ++r) {
    float4 v = make_float4(acc[r][0], acc[r][1], acc[r][2], acc[r][3]);
    *(float4*)(ob + ((size_t)r << 10)) = v;
  }
  if (blk == 0 && tid == 0) {
    float s = 0.f;
    for (int i = 0; i < 32; ++i) s += ssum[i];
    out[6291456] = 32.f * s;   // H*W * mean over batch of sum(s)
  }
}

extern "C" void kernel_launch(void* const* d_in, const int* in_sizes, int n_in,
                              void* d_out, int out_size, void* d_ws, size_t ws_size,
                              hipStream_t stream) {
  const float* inp = (const float*)d_in[0];
  const float* wlo = (const float*)d_in[1];
  const float* cw  = (const float*)d_in[2];
  const float* cb  = (const float*)d_in[3];
  const float* lw  = (const float*)d_in[4];
  const float* lb  = (const float*)d_in[5];
  const float* ss  = (const float*)d_in[6];
  float* out = (float*)d_out;
  float* ws = (float*)d_ws;
  // ws layout (floats): hpart 262144 | h_t 65536 | mats 1179648 | ssum 32  (~6 MB)
  float* hpart = ws;
  float* h_t   = ws + 262144;
  float* mats  = ws + 327680;
  float* ssum  = ws + 1507328;
  hipLaunchKernelGGL(conv_kernel,    dim3(128), dim3(256), 0, stream, wlo, cw, hpart);
  hipLaunchKernelGGL(hreduce_kernel, dim3(256), dim3(256), 0, stream, hpart, cb, h_t);
  hipLaunchKernelGGL(linear_kernel,  dim3(576), dim3(256), 0, stream, h_t, lw, lb, mats);
  hipLaunchKernelGGL(lu_kernel,      dim3(32),  dim3(768), 0, stream, mats, ss, ssum);
  hipLaunchKernelGGL(out_kernel,     dim3(768), dim3(256), 0, stream, mats, inp, ssum, out);
}

// Round 6
// 500.046 us; speedup vs baseline: 1.7616x; 1.3753x over previous
//
#include <hip/hip_runtime.h>
#include <math.h>

// Problem: B=32, C=192, H=W=32, CH=8, stride=2 -> FEAT=2048, N=C*C=36864
// Pipeline: conv(+relu) -> linear -> per-batch LU (partial pivot) ->
//           weight = mats + P*(L*diag(d)) in-place -> out = weight @ inp ; logdet.

#define NFEAT 2048
#define NN    36864

// ---------------- Stage 1: conv partials (c-sliced) ----------------
__global__ __launch_bounds__(256) void conv_kernel(const float* __restrict__ w,
                                                   const float* __restrict__ cw,
                                                   float* __restrict__ hpart) {
  int blk = blockIdx.x;
  int b = blk >> 2, cs = blk & 3;
  int tid = threadIdx.x;
  int oy = tid >> 4, ox = tid & 15;
  __shared__ float wlds[8 * 48 * 9];
  for (int idx = tid; idx < 8 * 48 * 9; idx += 256) {
    int ch = idx / 432, rem = idx - ch * 432;
    int c = rem / 9, kk = rem - c * 9;
    wlds[idx] = cw[ch * 1728 + (cs * 48 + c) * 9 + kk];
  }
  __syncthreads();
  float acc[8];
#pragma unroll
  for (int ch = 0; ch < 8; ++ch) acc[ch] = 0.f;
  const float* img0 = w + (((size_t)b * 192 + cs * 48) << 10);
  for (int c = 0; c < 48; ++c) {
    const float* img = img0 + ((size_t)c << 10);
    float iv[9];
#pragma unroll
    for (int ky = 0; ky < 3; ++ky)
#pragma unroll
      for (int kx = 0; kx < 3; ++kx) {
        int iy = 2 * oy - 1 + ky, ix = 2 * ox - 1 + kx;
        bool ok = (iy >= 0) & (iy < 32) & (ix >= 0) & (ix < 32);
        iv[ky * 3 + kx] = ok ? img[iy * 32 + ix] : 0.f;
      }
#pragma unroll
    for (int ch = 0; ch < 8; ++ch) {
      const float* wp = &wlds[(ch * 48 + c) * 9];
      float s = acc[ch];
#pragma unroll
      for (int t = 0; t < 9; ++t) s = fmaf(iv[t], wp[t], s);
      acc[ch] = s;
    }
  }
  size_t base = ((size_t)(cs * 32 + b) << 11) + tid;
#pragma unroll
  for (int ch = 0; ch < 8; ++ch) hpart[base + (ch << 8)] = acc[ch];
}

// ---------------- Stage 2: reduce partials + bias + relu -> h_t[k][b] --------------
__global__ __launch_bounds__(256) void hreduce_kernel(const float* __restrict__ hpart,
                                                      const float* __restrict__ cb,
                                                      float* __restrict__ h_t) {
  int g = blockIdx.x * 256 + threadIdx.x;   // 0..65535
  int k = g & 2047, b = g >> 11;
  float s = 0.f;
#pragma unroll
  for (int cs = 0; cs < 4; ++cs) s += hpart[(((size_t)(cs * 32 + b)) << 11) + k];
  s += cb[k >> 8];
  s = fmaxf(s, 0.f);
  h_t[((size_t)k << 5) + b] = s;
}

// ---------------- Stage 3: linear  mats[b][n] = sum_k h[b][k]*lw[n][k] + lb[n] ------
__global__ __launch_bounds__(256) void linear_kernel(const float* __restrict__ h_t,
                                                     const float* __restrict__ lw,
                                                     const float* __restrict__ lb,
                                                     float* __restrict__ mats) {
  __shared__ float smem[4 * 64 * 68];   // W staging; aliased as accbuf[4][64][33]
  int tid = threadIdx.x;
  int l = tid & 63;
  int wq = __builtin_amdgcn_readfirstlane(tid >> 6);
  int n0 = blockIdx.x << 6;
  int kbase = wq << 9;
  float* wl = smem + wq * (64 * 68);
  float acc[32];
#pragma unroll
  for (int i = 0; i < 32; ++i) acc[i] = 0.f;
  for (int kc = 0; kc < 8; ++kc) {
    int koff = kbase + (kc << 6);
#pragma unroll
    for (int j = 0; j < 16; ++j) {
      int f = l + (j << 6);
      int row = f >> 4, c4 = (f & 15) << 2;
      float4 v = *(const float4*)(lw + (size_t)(n0 + row) * 2048 + koff + c4);
      *(float4*)(wl + row * 68 + c4) = v;
    }
#pragma unroll 2
    for (int kk = 0; kk < 64; ++kk) {
      float wv = wl[l * 68 + kk];
      const float4* hp = (const float4*)(h_t + ((size_t)(koff + kk) << 5));
#pragma unroll
      for (int q = 0; q < 8; ++q) {
        float4 hv = hp[q];
        acc[4 * q + 0] = fmaf(hv.x, wv, acc[4 * q + 0]);
        acc[4 * q + 1] = fmaf(hv.y, wv, acc[4 * q + 1]);
        acc[4 * q + 2] = fmaf(hv.z, wv, acc[4 * q + 2]);
        acc[4 * q + 3] = fmaf(hv.w, wv, acc[4 * q + 3]);
      }
    }
  }
  __syncthreads();
  float* accbuf = smem;                  // [4][64][33]
  float* mine = accbuf + (wq * 64 + l) * 33;
#pragma unroll
  for (int i = 0; i < 32; ++i) mine[i] = acc[i];
  __syncthreads();
#pragma unroll
  for (int r = 0; r < 8; ++r) {
    int q = r * 256 + tid;               // 0..2047
    int nsub = q & 63, b = q >> 6;
    float s = accbuf[(0 * 64 + nsub) * 33 + b] + accbuf[(1 * 64 + nsub) * 33 + b] +
              accbuf[(2 * 64 + nsub) * 33 + b] + accbuf[(3 * 64 + nsub) * 33 + b];
    s += lb[n0 + nsub];
    mats[(size_t)b * NN + n0 + nsub] = s;
  }
}

// ---------------- Stage 4: per-batch BLOCKED LU (NB=8), LDS-resident ----------
// R5 post-mortem: rank-1 structure = 192 x (serial strided pivot scan + 2 barriers
// + latency-exposed RMW) -> 405us at VALUBusy 1.1%. Fix: panel factorization in
// wave0 REGISTERS (named float4s, no allocas -> no promotion failure; zero barriers,
// zero LDS column scans), then rank-8 trailing update (TRSM-in-regs + 8-deep fmaf
// chain; ~6x less LDS traffic; 48 barriers total). Arithmetic is op-for-op identical
// to R2-R5 (same pivot rule, same fmaf order) -> bit-identical output.
#define CAT_(A, B) A##B
#define CAT(A, B) CAT_(A, B)
#define PR_0(R) CAT(pA, R).x
#define PR_1(R) CAT(pA, R).y
#define PR_2(R) CAT(pA, R).z
#define PR_3(R) CAT(pA, R).w
#define PR_4(R) CAT(pB, R).x
#define PR_5(R) CAT(pB, R).y
#define PR_6(R) CAT(pB, R).z
#define PR_7(R) CAT(pB, R).w
#define PR(R, K) CAT(PR_, K)(R)
#define UU_0 uA.x
#define UU_1 uA.y
#define UU_2 uA.z
#define UU_3 uA.w
#define UU_4 uB.x
#define UU_5 uB.y
#define UU_6 uB.z
#define UU_7 uB.w
#define UU(K) CAT(UU_, K)
#define UPDJ(R, J) PR(R, J) = fmaf(-m, UU(J), PR(R, J));
#define TAIL_0(R) UPDJ(R,1) UPDJ(R,2) UPDJ(R,3) UPDJ(R,4) UPDJ(R,5) UPDJ(R,6) UPDJ(R,7)
#define TAIL_1(R) UPDJ(R,2) UPDJ(R,3) UPDJ(R,4) UPDJ(R,5) UPDJ(R,6) UPDJ(R,7)
#define TAIL_2(R) UPDJ(R,3) UPDJ(R,4) UPDJ(R,5) UPDJ(R,6) UPDJ(R,7)
#define TAIL_3(R) UPDJ(R,4) UPDJ(R,5) UPDJ(R,6) UPDJ(R,7)
#define TAIL_4(R) UPDJ(R,5) UPDJ(R,6) UPDJ(R,7)
#define TAIL_5(R) UPDJ(R,6) UPDJ(R,7)
#define TAIL_6(R) UPDJ(R,7)
#define TAIL_7(R)
#define UPDROW(R, KK, kg)                                                      \
  if (CAT(lg, R) > (kg)) {                                                     \
    float m = PR(R, KK) * recip;                                               \
    PR(R, KK) = m;                                                             \
    CAT(TAIL_, KK)(R)                                                          \
  }
#define PSTEP(KK) {                                                            \
  const int kg = kp + KK;                                                      \
  float bv = -1.f; int br = 0x7fffffff;                                        \
  { float v = fabsf(PR(0,KK)); if (lg0 >= kg && (v > bv || (v == bv && lg0 < br))) { bv = v; br = lg0; } } \
  { float v = fabsf(PR(1,KK)); if (lg1 >= kg && (v > bv || (v == bv && lg1 < br))) { bv = v; br = lg1; } } \
  { float v = fabsf(PR(2,KK)); if (lg2 >= kg && (v > bv || (v == bv && lg2 < br))) { bv = v; br = lg2; } } \
  for (int msk = 1; msk <= 32; msk <<= 1) {                                    \
    float ov = __shfl_xor(bv, msk, 64);                                        \
    int obr = __shfl_xor(br, msk, 64);                                         \
    if (ov > bv || (ov == bv && obr < br)) { bv = ov; br = obr; }              \
  }                                                                            \
  bool own0 = (lg0 == br), own1 = (lg1 == br), own2 = (lg2 == br);             \
  float4 sA = own1 ? pA1 : (own2 ? pA2 : pA0);                                 \
  float4 sB = own1 ? pB1 : (own2 ? pB2 : pB0);                                 \
  int owner = (int)__ffsll(__ballot(own0 | own1 | own2)) - 1;                  \
  float4 uA, uB;                                                               \
  uA.x = __shfl(sA.x, owner); uA.y = __shfl(sA.y, owner);                      \
  uA.z = __shfl(sA.z, owner); uA.w = __shfl(sA.w, owner);                      \
  uB.x = __shfl(sB.x, owner); uB.y = __shfl(sB.y, owner);                      \
  uB.z = __shfl(sB.z, owner); uB.w = __shfl(sB.w, owner);                      \
  float piv = UU(KK);                                                          \
  float recip = 1.0f / piv;                                                    \
  if (tid == 0) {                                                              \
    diagU[kg] = piv;                                                           \
    int t0 = rowmap[kg], t1 = rowmap[br];                                      \
    rowmap[kg] = t1; rowmap[br] = t0;                                          \
  }                                                                            \
  lg0 = (lg0 == kg) ? br : ((lg0 == br) ? kg : lg0);                           \
  lg1 = (lg1 == kg) ? br : ((lg1 == br) ? kg : lg1);                           \
  lg2 = (lg2 == kg) ? br : ((lg2 == br) ? kg : lg2);                           \
  UPDROW(0, KK, kg)                                                            \
  UPDROW(1, KK, kg)                                                            \
  UPDROW(2, KK, kg)                                                            \
}
#define FMA4(D, M, S) {                                                        \
  float mm = (M);                                                              \
  D.x = fmaf(-mm, S.x, D.x); D.y = fmaf(-mm, S.y, D.y);                        \
  D.z = fmaf(-mm, S.z, D.z); D.w = fmaf(-mm, S.w, D.w);                        \
}

__global__ __launch_bounds__(768, 1) void lu_kernel(float* __restrict__ A0,
                                                    const float* __restrict__ ssign,
                                                    float* __restrict__ ssum) {
  __shared__ float4 As4[192 * 49];     // 150528 B, row stride 49 float4
  __shared__ int rowmap[192];
  __shared__ float diagU[192];
  __shared__ float4 dval4[48];
  float* As = (float*)As4;
  float* dvalf = (float*)dval4;
  (void)As;
  int b = blockIdx.x;
  int tid = threadIdx.x;
  float* __restrict__ A = A0 + (size_t)b * NN;

  // load A -> LDS (coalesced float4)
#pragma unroll
  for (int j = 0; j < 12; ++j) {
    int chunk = tid + 768 * j;
    int row = chunk / 48, q = chunk - row * 48;
    As4[row * 49 + q] = *(const float4*)(A + row * 192 + 4 * q);
  }
  for (int i = tid; i < 192; i += 768) rowmap[i] = i;
  __syncthreads();

  int lg0 = tid, lg1 = tid + 64, lg2 = tid + 128;   // logical pos of wave0's rows

  for (int p = 0; p < 24; ++p) {
    const int kp = p << 3;
    const int pc = kp >> 2;
    // ---- panel factorization: wave 0, all in registers, no barriers ----
    if (tid < 64) {
      float4 pA0 = As4[tid * 49 + pc],         pB0 = As4[tid * 49 + pc + 1];
      float4 pA1 = As4[(tid + 64) * 49 + pc],  pB1 = As4[(tid + 64) * 49 + pc + 1];
      float4 pA2 = As4[(tid + 128) * 49 + pc], pB2 = As4[(tid + 128) * 49 + pc + 1];
      PSTEP(0) PSTEP(1) PSTEP(2) PSTEP(3) PSTEP(4) PSTEP(5) PSTEP(6) PSTEP(7)
      As4[tid * 49 + pc] = pA0;         As4[tid * 49 + pc + 1] = pB0;
      As4[(tid + 64) * 49 + pc] = pA1;  As4[(tid + 64) * 49 + pc + 1] = pB1;
      As4[(tid + 128) * 49 + pc] = pA2; As4[(tid + 128) * 49 + pc + 1] = pB2;
    }
    __syncthreads();  // panel (L block, rowmap, diagU) visible
    // ---- trailing: per-chunk TRSM into regs, then rank-8 GEMM ----
    {
      const int qp1 = (kp + 8) >> 2;
      const int q = tid >> 4;        // 0..47 chunk column
      const int slot = tid & 15;
      if (q >= qp1) {
        const int ur0 = rowmap[kp + 0], ur1 = rowmap[kp + 1];
        const int ur2 = rowmap[kp + 2], ur3 = rowmap[kp + 3];
        const int ur4 = rowmap[kp + 4], ur5 = rowmap[kp + 5];
        const int ur6 = rowmap[kp + 6], ur7 = rowmap[kp + 7];
        float4 u40 = As4[ur0 * 49 + q], u41 = As4[ur1 * 49 + q];
        float4 u42 = As4[ur2 * 49 + q], u43 = As4[ur3 * 49 + q];
        float4 u44 = As4[ur4 * 49 + q], u45 = As4[ur5 * 49 + q];
        float4 u46 = As4[ur6 * 49 + q], u47 = As4[ur7 * 49 + q];
        // TRSM (unit-lower 8x8 panel triangle), sequential v ascending
        { float4 la = As4[ur1 * 49 + pc];
          FMA4(u41, la.x, u40) }
        { float4 la = As4[ur2 * 49 + pc];
          FMA4(u42, la.x, u40) FMA4(u42, la.y, u41) }
        { float4 la = As4[ur3 * 49 + pc];
          FMA4(u43, la.x, u40) FMA4(u43, la.y, u41) FMA4(u43, la.z, u42) }
        { float4 la = As4[ur4 * 49 + pc];
          FMA4(u44, la.x, u40) FMA4(u44, la.y, u41) FMA4(u44, la.z, u42) FMA4(u44, la.w, u43) }
        { float4 la = As4[ur5 * 49 + pc]; float4 lb = As4[ur5 * 49 + pc + 1];
          FMA4(u45, la.x, u40) FMA4(u45, la.y, u41) FMA4(u45, la.z, u42) FMA4(u45, la.w, u43)
          FMA4(u45, lb.x, u44) }
        { float4 la = As4[ur6 * 49 + pc]; float4 lb = As4[ur6 * 49 + pc + 1];
          FMA4(u46, la.x, u40) FMA4(u46, la.y, u41) FMA4(u46, la.z, u42) FMA4(u46, la.w, u43)
          FMA4(u46, lb.x, u44) FMA4(u46, lb.y, u45) }
        { float4 la = As4[ur7 * 49 + pc]; float4 lb = As4[ur7 * 49 + pc + 1];
          FMA4(u47, la.x, u40) FMA4(u47, la.y, u41) FMA4(u47, la.z, u42) FMA4(u47, la.w, u43)
          FMA4(u47, lb.x, u44) FMA4(u47, lb.y, u45) FMA4(u47, lb.z, u46) }
        // GEMM: rows logical s > kp+7, 8-deep fmaf chain (t ascending)
        for (int i = 0; i < 12; ++i) {
          int s = slot + (i << 4);
          if (s >= kp + 8) {
            int phys = rowmap[s];
            float4 la = As4[phys * 49 + pc];
            float4 lb = As4[phys * 49 + pc + 1];
            float4 c = As4[phys * 49 + q];
            FMA4(c, la.x, u40) FMA4(c, la.y, u41) FMA4(c, la.z, u42) FMA4(c, la.w, u43)
            FMA4(c, lb.x, u44) FMA4(c, lb.y, u45) FMA4(c, lb.z, u46) FMA4(c, lb.w, u47)
            As4[phys * 49 + q] = c;
          }
        }
      }
    }
    __syncthreads();  // trailing matrix ready for next panel
  }

  // ---- epilogue: logdet partial, dval, weight = mats + P*(L*diag(d)) ----
  if (tid == 0) {
    float s = 0.f;
    for (int i = 0; i < 192; ++i) s += diagU[i];
    ssum[b] = s;
  }
  if (tid < 192) dvalf[tid] = ssign[tid] * expf(diagU[tid]) - diagU[tid];
  __syncthreads();
  {
    const int r = tid >> 2;
    const int tq = tid & 3;
    int i = r;
    int phys = rowmap[r];
    float di = dvalf[i];
    float* __restrict__ G = A + (size_t)phys * 192;   // output row = original row phys
    int qi = i >> 2;
    for (int j = 0; j < 12; ++j) {
      int q = tq + 4 * j;
      if (q > qi) continue;
      float4 g4 = *(float4*)(G + 4 * q);
      float4 a4 = As4[phys * 49 + q];
      float4 d4 = dval4[q];
      if (q == qi) {                              // boundary chunk: per-element
        int c0 = 4 * q;
        g4.x = (c0 + 0 < i) ? g4.x + a4.x * d4.x : ((c0 + 0 == i) ? g4.x + di : g4.x);
        g4.y = (c0 + 1 < i) ? g4.y + a4.y * d4.y : ((c0 + 1 == i) ? g4.y + di : g4.y);
        g4.z = (c0 + 2 < i) ? g4.z + a4.z * d4.z : ((c0 + 2 == i) ? g4.z + di : g4.z);
        g4.w = (c0 + 3 < i) ? g4.w + a4.w * d4.w : ((c0 + 3 == i) ? g4.w + di : g4.w);
      } else {                                    // full chunk: all cols < i
        g4.x += a4.x * d4.x;
        g4.y += a4.y * d4.y;
        g4.z += a4.z * d4.z;
        g4.w += a4.w * d4.w;
      }
      *(float4*)(G + 4 * q) = g4;
    }
  }
}

// ---------------- Stage 5: out[b] = weight[b] @ inp[b]  (+ logdet write) ----------
__global__ __launch_bounds__(256) void out_kernel(const float* __restrict__ wt,
                                                  const float* __restrict__ inp,
                                                  const float* __restrict__ ssum,
                                                  float* __restrict__ out) {
  int blk = blockIdx.x;
  int b = blk / 24, rem = blk % 24;
  int it = rem >> 3, jt = rem & 7;
  int i0 = it << 6, hw0 = jt << 7;
  int tid = threadIdx.x;
  int tx = tid & 31, ty = tid >> 5;
  __shared__ float wlds[64 * 36];
  __shared__ float xlds[32 * 128];
  const float* wb = wt + (size_t)b * NN;
  const float* xb = inp + (((size_t)b * 192) << 10);
  float acc[8][4];
#pragma unroll
  for (int r = 0; r < 8; ++r)
#pragma unroll
    for (int c = 0; c < 4; ++c) acc[r][c] = 0.f;
  for (int kc = 0; kc < 6; ++kc) {
    __syncthreads();
#pragma unroll
    for (int j = 0; j < 2; ++j) {
      int f4 = tid + (j << 8);
      int row = f4 >> 3, c4 = (f4 & 7) << 2;
      float4 v = *(const float4*)(wb + (size_t)(i0 + row) * 192 + (kc << 5) + c4);
      *(float4*)(wlds + row * 36 + c4) = v;
    }
#pragma unroll
    for (int j = 0; j < 4; ++j) {
      int f4 = tid + (j << 8);
      int row = f4 >> 5, c4 = (f4 & 31) << 2;
      float4 v = *(const float4*)(xb + (((size_t)(kc << 5) + row) << 10) + hw0 + c4);
      *(float4*)(xlds + (row << 7) + c4) = v;
    }
    __syncthreads();
#pragma unroll 4
    for (int k = 0; k < 32; ++k) {
      float4 xv = *(const float4*)(xlds + (k << 7) + (tx << 2));
      float wr[8];
#pragma unroll
      for (int r = 0; r < 8; ++r) wr[r] = wlds[(ty * 8 + r) * 36 + k];
#pragma unroll
      for (int r = 0; r < 8; ++r) {
        acc[r][0] = fmaf(wr[r], xv.x, acc[r][0]);
        acc[r][1] = fmaf(wr[r], xv.y, acc[r][1]);
        acc[r][2] = fmaf(wr[r], xv.z, acc[r][2]);
        acc[r][3] = fmaf(wr[r], xv.w, acc[r][3]);
      }
    }
  }
  float* ob = out + (((size_t)b * 192 + i0 + ty * 8) << 10) + hw0 + (tx << 2);
#pragma unroll
  for (int r = 0; r < 8; ++r) {
    float4 v = make_float4(acc[r][0], acc[r][1], acc[r][2], acc[r][3]);
    *(float4*)(ob + ((size_t)r << 10)) = v;
  }
  if (blk == 0 && tid == 0) {
    float s = 0.f;
    for (int i = 0; i < 32; ++i) s += ssum[i];
    out[6291456] = 32.f * s;   // H*W * mean over batch of sum(s)
  }
}

extern "C" void kernel_launch(void* const* d_in, const int* in_sizes, int n_in,
                              void* d_out, int out_size, void* d_ws, size_t ws_size,
                              hipStream_t stream) {
  const float* inp = (const float*)d_in[0];
  const float* wlo = (const float*)d_in[1];
  const float* cw  = (const float*)d_in[2];
  const float* cb  = (const float*)d_in[3];
  const float* lw  = (const float*)d_in[4];
  const float* lb  = (const float*)d_in[5];
  const float* ss  = (const float*)d_in[6];
  float* out = (float*)d_out;
  float* ws = (float*)d_ws;
  // ws layout (floats): hpart 262144 | h_t 65536 | mats 1179648 | ssum 32  (~6 MB)
  float* hpart = ws;
  float* h_t   = ws + 262144;
  float* mats  = ws + 327680;
  float* ssum  = ws + 1507328;
  hipLaunchKernelGGL(conv_kernel,    dim3(128), dim3(256), 0, stream, wlo, cw, hpart);
  hipLaunchKernelGGL(hreduce_kernel, dim3(256), dim3(256), 0, stream, hpart, cb, h_t);
  hipLaunchKernelGGL(linear_kernel,  dim3(576), dim3(256), 0, stream, h_t, lw, lb, mats);
  hipLaunchKernelGGL(lu_kernel,      dim3(32),  dim3(768), 0, stream, mats, ss, ssum);
  hipLaunchKernelGGL(out_kernel,     dim3(768), dim3(256), 0, stream, mats, inp, ssum, out);
}

// Round 7
// 489.465 us; speedup vs baseline: 1.7997x; 1.0216x over previous
//
#include <hip/hip_runtime.h>
#include <math.h>

// Problem: B=32, C=192, H=W=32, CH=8, stride=2 -> FEAT=2048, N=C*C=36864
// Pipeline: conv(+relu) -> linear -> per-batch LU (partial pivot) ->
//           weight = mats + P*(L*diag(d)) in-place -> out = weight @ inp ; logdet.

#define NFEAT 2048
#define NN    36864

// ---------------- Stage 1: conv partials (c-sliced) ----------------
__global__ __launch_bounds__(256) void conv_kernel(const float* __restrict__ w,
                                                   const float* __restrict__ cw,
                                                   float* __restrict__ hpart) {
  int blk = blockIdx.x;
  int b = blk >> 2, cs = blk & 3;
  int tid = threadIdx.x;
  int oy = tid >> 4, ox = tid & 15;
  __shared__ float wlds[8 * 48 * 9];
  for (int idx = tid; idx < 8 * 48 * 9; idx += 256) {
    int ch = idx / 432, rem = idx - ch * 432;
    int c = rem / 9, kk = rem - c * 9;
    wlds[idx] = cw[ch * 1728 + (cs * 48 + c) * 9 + kk];
  }
  __syncthreads();
  float acc[8];
#pragma unroll
  for (int ch = 0; ch < 8; ++ch) acc[ch] = 0.f;
  const float* img0 = w + (((size_t)b * 192 + cs * 48) << 10);
  for (int c = 0; c < 48; ++c) {
    const float* img = img0 + ((size_t)c << 10);
    float iv[9];
#pragma unroll
    for (int ky = 0; ky < 3; ++ky)
#pragma unroll
      for (int kx = 0; kx < 3; ++kx) {
        int iy = 2 * oy - 1 + ky, ix = 2 * ox - 1 + kx;
        bool ok = (iy >= 0) & (iy < 32) & (ix >= 0) & (ix < 32);
        iv[ky * 3 + kx] = ok ? img[iy * 32 + ix] : 0.f;
      }
#pragma unroll
    for (int ch = 0; ch < 8; ++ch) {
      const float* wp = &wlds[(ch * 48 + c) * 9];
      float s = acc[ch];
#pragma unroll
      for (int t = 0; t < 9; ++t) s = fmaf(iv[t], wp[t], s);
      acc[ch] = s;
    }
  }
  size_t base = ((size_t)(cs * 32 + b) << 11) + tid;
#pragma unroll
  for (int ch = 0; ch < 8; ++ch) hpart[base + (ch << 8)] = acc[ch];
}

// ---------------- Stage 2: reduce partials + bias + relu -> h_t[k][b] --------------
__global__ __launch_bounds__(256) void hreduce_kernel(const float* __restrict__ hpart,
                                                      const float* __restrict__ cb,
                                                      float* __restrict__ h_t) {
  int g = blockIdx.x * 256 + threadIdx.x;   // 0..65535
  int k = g & 2047, b = g >> 11;
  float s = 0.f;
#pragma unroll
  for (int cs = 0; cs < 4; ++cs) s += hpart[(((size_t)(cs * 32 + b)) << 11) + k];
  s += cb[k >> 8];
  s = fmaxf(s, 0.f);
  h_t[((size_t)k << 5) + b] = s;
}

// ---------------- Stage 3: linear  mats[b][n] = sum_k h[b][k]*lw[n][k] + lb[n] ------
// R6 post-mortem: old structure issued 4096 uniform VMEM h-loads/thread at 15%
// occupancy -> latency-bound, 224us @ 688GB/s. v2: stage h AND W chunks in LDS,
// thread owns 8n x 1b (acc in regs), inner loop = pure conflict-free LDS + fmaf.
// BIT-EXACT vs R2-R6: four named quarter-accumulators filled in ascending-k fmaf
// order, combined ((q0+q1)+q2)+q3 then +lb -- same summation tree as the old
// 4-wave-quarter + cross-wave-reduce kernel -> mats bits identical -> LU pivots
// identical.
__global__ __launch_bounds__(256) void linear_kernel(const float* __restrict__ h_t,
                                                     const float* __restrict__ lw,
                                                     const float* __restrict__ lb,
                                                     float* __restrict__ mats) {
  __shared__ float Wbuf[64 * 68];   // 17.4 KB, row stride 68 (16B-aligned, pad)
  __shared__ float Hbuf[64 * 36];   // 9.2 KB, k-major stride 36: bank (4k+b)%32
  int tid = threadIdx.x;
  int n0 = blockIdx.x << 6;
  int half = tid >> 5;              // 0..7 -> n sub-block
  int bb = tid & 31;                // batch owned by this thread
  int nb = half << 3;               // local n base (0..56)
  float accq0[8], accq1[8], accq2[8], accq3[8];
#pragma unroll
  for (int j = 0; j < 8; ++j) { accq0[j] = 0.f; accq1[j] = 0.f; accq2[j] = 0.f; accq3[j] = 0.f; }

#define LIN_CHUNK(ACC)                                                         \
  {                                                                            \
    int koff = kc << 6;                                                        \
    _Pragma("unroll") for (int j = 0; j < 4; ++j) {                            \
      int f = tid + (j << 8);                                                  \
      int row = f >> 4, c4 = (f & 15) << 2;                                    \
      *(float4*)(Wbuf + row * 68 + c4) =                                       \
          *(const float4*)(lw + (size_t)(n0 + row) * 2048 + koff + c4);        \
    }                                                                          \
    _Pragma("unroll") for (int j = 0; j < 2; ++j) {                            \
      int f = tid + (j << 8);                                                  \
      int kr = f >> 3, b4 = (f & 7) << 2;                                      \
      *(float4*)(Hbuf + kr * 36 + b4) =                                        \
          *(const float4*)(h_t + (((size_t)(koff + kr)) << 5) + b4);           \
    }                                                                          \
    __syncthreads();                                                           \
    _Pragma("unroll 4") for (int k4 = 0; k4 < 16; ++k4) {                      \
      int kk = k4 << 2;                                                        \
      float h0 = Hbuf[(kk + 0) * 36 + bb];                                     \
      float h1 = Hbuf[(kk + 1) * 36 + bb];                                     \
      float h2 = Hbuf[(kk + 2) * 36 + bb];                                     \
      float h3 = Hbuf[(kk + 3) * 36 + bb];                                     \
      _Pragma("unroll") for (int j = 0; j < 8; ++j) {                          \
        float4 w4 = *(const float4*)(Wbuf + (nb + j) * 68 + kk);               \
        float s = ACC[j];                                                      \
        s = fmaf(w4.x, h0, s);                                                 \
        s = fmaf(w4.y, h1, s);                                                 \
        s = fmaf(w4.z, h2, s);                                                 \
        s = fmaf(w4.w, h3, s);                                                 \
        ACC[j] = s;                                                            \
      }                                                                        \
    }                                                                          \
    __syncthreads();                                                           \
  }

  for (int kc = 0; kc < 8; ++kc)  LIN_CHUNK(accq0)
  for (int kc = 8; kc < 16; ++kc) LIN_CHUNK(accq1)
  for (int kc = 16; kc < 24; ++kc) LIN_CHUNK(accq2)
  for (int kc = 24; kc < 32; ++kc) LIN_CHUNK(accq3)
#undef LIN_CHUNK

  // combine quarters left-to-right (old cross-wave reduce order), +bias, store
  float o[8];
#pragma unroll
  for (int j = 0; j < 8; ++j)
    o[j] = ((accq0[j] + accq1[j]) + accq2[j]) + accq3[j] + lb[n0 + nb + j];
  float* mp = mats + (size_t)bb * NN + n0 + nb;
  *(float4*)(mp + 0) = make_float4(o[0], o[1], o[2], o[3]);
  *(float4*)(mp + 4) = make_float4(o[4], o[5], o[6], o[7]);
}

// ---------------- Stage 4: per-batch BLOCKED LU (NB=8), LDS-resident ----------
// (unchanged from R6 -- panel in wave0 registers, rank-8 trailing update)
#define CAT_(A, B) A##B
#define CAT(A, B) CAT_(A, B)
#define PR_0(R) CAT(pA, R).x
#define PR_1(R) CAT(pA, R).y
#define PR_2(R) CAT(pA, R).z
#define PR_3(R) CAT(pA, R).w
#define PR_4(R) CAT(pB, R).x
#define PR_5(R) CAT(pB, R).y
#define PR_6(R) CAT(pB, R).z
#define PR_7(R) CAT(pB, R).w
#define PR(R, K) CAT(PR_, K)(R)
#define UU_0 uA.x
#define UU_1 uA.y
#define UU_2 uA.z
#define UU_3 uA.w
#define UU_4 uB.x
#define UU_5 uB.y
#define UU_6 uB.z
#define UU_7 uB.w
#define UU(K) CAT(UU_, K)
#define UPDJ(R, J) PR(R, J) = fmaf(-m, UU(J), PR(R, J));
#define TAIL_0(R) UPDJ(R,1) UPDJ(R,2) UPDJ(R,3) UPDJ(R,4) UPDJ(R,5) UPDJ(R,6) UPDJ(R,7)
#define TAIL_1(R) UPDJ(R,2) UPDJ(R,3) UPDJ(R,4) UPDJ(R,5) UPDJ(R,6) UPDJ(R,7)
#define TAIL_2(R) UPDJ(R,3) UPDJ(R,4) UPDJ(R,5) UPDJ(R,6) UPDJ(R,7)
#define TAIL_3(R) UPDJ(R,4) UPDJ(R,5) UPDJ(R,6) UPDJ(R,7)
#define TAIL_4(R) UPDJ(R,5) UPDJ(R,6) UPDJ(R,7)
#define TAIL_5(R) UPDJ(R,6) UPDJ(R,7)
#define TAIL_6(R) UPDJ(R,7)
#define TAIL_7(R)
#define UPDROW(R, KK, kg)                                                      \
  if (CAT(lg, R) > (kg)) {                                                     \
    float m = PR(R, KK) * recip;                                               \
    PR(R, KK) = m;                                                             \
    CAT(TAIL_, KK)(R)                                                          \
  }
#define PSTEP(KK) {                                                            \
  const int kg = kp + KK;                                                      \
  float bv = -1.f; int br = 0x7fffffff;                                        \
  { float v = fabsf(PR(0,KK)); if (lg0 >= kg && (v > bv || (v == bv && lg0 < br))) { bv = v; br = lg0; } } \
  { float v = fabsf(PR(1,KK)); if (lg1 >= kg && (v > bv || (v == bv && lg1 < br))) { bv = v; br = lg1; } } \
  { float v = fabsf(PR(2,KK)); if (lg2 >= kg && (v > bv || (v == bv && lg2 < br))) { bv = v; br = lg2; } } \
  for (int msk = 1; msk <= 32; msk <<= 1) {                                    \
    float ov = __shfl_xor(bv, msk, 64);                                        \
    int obr = __shfl_xor(br, msk, 64);                                         \
    if (ov > bv || (ov == bv && obr < br)) { bv = ov; br = obr; }              \
  }                                                                            \
  bool own0 = (lg0 == br), own1 = (lg1 == br), own2 = (lg2 == br);             \
  float4 sA = own1 ? pA1 : (own2 ? pA2 : pA0);                                 \
  float4 sB = own1 ? pB1 : (own2 ? pB2 : pB0);                                 \
  int owner = (int)__ffsll(__ballot(own0 | own1 | own2)) - 1;                  \
  float4 uA, uB;                                                               \
  uA.x = __shfl(sA.x, owner); uA.y = __shfl(sA.y, owner);                      \
  uA.z = __shfl(sA.z, owner); uA.w = __shfl(sA.w, owner);                      \
  uB.x = __shfl(sB.x, owner); uB.y = __shfl(sB.y, owner);                      \
  uB.z = __shfl(sB.z, owner); uB.w = __shfl(sB.w, owner);                      \
  float piv = UU(KK);                                                          \
  float recip = 1.0f / piv;                                                    \
  if (tid == 0) {                                                              \
    diagU[kg] = piv;                                                           \
    int t0 = rowmap[kg], t1 = rowmap[br];                                      \
    rowmap[kg] = t1; rowmap[br] = t0;                                          \
  }                                                                            \
  lg0 = (lg0 == kg) ? br : ((lg0 == br) ? kg : lg0);                           \
  lg1 = (lg1 == kg) ? br : ((lg1 == br) ? kg : lg1);                           \
  lg2 = (lg2 == kg) ? br : ((lg2 == br) ? kg : lg2);                           \
  UPDROW(0, KK, kg)                                                            \
  UPDROW(1, KK, kg)                                                            \
  UPDROW(2, KK, kg)                                                            \
}
#define FMA4(D, M, S) {                                                        \
  float mm = (M);                                                              \
  D.x = fmaf(-mm, S.x, D.x); D.y = fmaf(-mm, S.y, D.y);                        \
  D.z = fmaf(-mm, S.z, D.z); D.w = fmaf(-mm, S.w, D.w);                        \
}

__global__ __launch_bounds__(768, 1) void lu_kernel(float* __restrict__ A0,
                                                    const float* __restrict__ ssign,
                                                    float* __restrict__ ssum) {
  __shared__ float4 As4[192 * 49];     // 150528 B, row stride 49 float4
  __shared__ int rowmap[192];
  __shared__ float diagU[192];
  __shared__ float4 dval4[48];
  float* As = (float*)As4;
  float* dvalf = (float*)dval4;
  (void)As;
  int b = blockIdx.x;
  int tid = threadIdx.x;
  float* __restrict__ A = A0 + (size_t)b * NN;

#pragma unroll
  for (int j = 0; j < 12; ++j) {
    int chunk = tid + 768 * j;
    int row = chunk / 48, q = chunk - row * 48;
    As4[row * 49 + q] = *(const float4*)(A + row * 192 + 4 * q);
  }
  for (int i = tid; i < 192; i += 768) rowmap[i] = i;
  __syncthreads();

  int lg0 = tid, lg1 = tid + 64, lg2 = tid + 128;   // logical pos of wave0's rows

  for (int p = 0; p < 24; ++p) {
    const int kp = p << 3;
    const int pc = kp >> 2;
    if (tid < 64) {
      float4 pA0 = As4[tid * 49 + pc],         pB0 = As4[tid * 49 + pc + 1];
      float4 pA1 = As4[(tid + 64) * 49 + pc],  pB1 = As4[(tid + 64) * 49 + pc + 1];
      float4 pA2 = As4[(tid + 128) * 49 + pc], pB2 = As4[(tid + 128) * 49 + pc + 1];
      PSTEP(0) PSTEP(1) PSTEP(2) PSTEP(3) PSTEP(4) PSTEP(5) PSTEP(6) PSTEP(7)
      As4[tid * 49 + pc] = pA0;         As4[tid * 49 + pc + 1] = pB0;
      As4[(tid + 64) * 49 + pc] = pA1;  As4[(tid + 64) * 49 + pc + 1] = pB1;
      As4[(tid + 128) * 49 + pc] = pA2; As4[(tid + 128) * 49 + pc + 1] = pB2;
    }
    __syncthreads();  // panel (L block, rowmap, diagU) visible
    {
      const int qp1 = (kp + 8) >> 2;
      const int q = tid >> 4;        // 0..47 chunk column
      const int slot = tid & 15;
      if (q >= qp1) {
        const int ur0 = rowmap[kp + 0], ur1 = rowmap[kp + 1];
        const int ur2 = rowmap[kp + 2], ur3 = rowmap[kp + 3];
        const int ur4 = rowmap[kp + 4], ur5 = rowmap[kp + 5];
        const int ur6 = rowmap[kp + 6], ur7 = rowmap[kp + 7];
        float4 u40 = As4[ur0 * 49 + q], u41 = As4[ur1 * 49 + q];
        float4 u42 = As4[ur2 * 49 + q], u43 = As4[ur3 * 49 + q];
        float4 u44 = As4[ur4 * 49 + q], u45 = As4[ur5 * 49 + q];
        float4 u46 = As4[ur6 * 49 + q], u47 = As4[ur7 * 49 + q];
        { float4 la = As4[ur1 * 49 + pc];
          FMA4(u41, la.x, u40) }
        { float4 la = As4[ur2 * 49 + pc];
          FMA4(u42, la.x, u40) FMA4(u42, la.y, u41) }
        { float4 la = As4[ur3 * 49 + pc];
          FMA4(u43, la.x, u40) FMA4(u43, la.y, u41) FMA4(u43, la.z, u42) }
        { float4 la = As4[ur4 * 49 + pc];
          FMA4(u44, la.x, u40) FMA4(u44, la.y, u41) FMA4(u44, la.z, u42) FMA4(u44, la.w, u43) }
        { float4 la = As4[ur5 * 49 + pc]; float4 lb = As4[ur5 * 49 + pc + 1];
          FMA4(u45, la.x, u40) FMA4(u45, la.y, u41) FMA4(u45, la.z, u42) FMA4(u45, la.w, u43)
          FMA4(u45, lb.x, u44) }
        { float4 la = As4[ur6 * 49 + pc]; float4 lb = As4[ur6 * 49 + pc + 1];
          FMA4(u46, la.x, u40) FMA4(u46, la.y, u41) FMA4(u46, la.z, u42) FMA4(u46, la.w, u43)
          FMA4(u46, lb.x, u44) FMA4(u46, lb.y, u45) }
        { float4 la = As4[ur7 * 49 + pc]; float4 lb = As4[ur7 * 49 + pc + 1];
          FMA4(u47, la.x, u40) FMA4(u47, la.y, u41) FMA4(u47, la.z, u42) FMA4(u47, la.w, u43)
          FMA4(u47, lb.x, u44) FMA4(u47, lb.y, u45) FMA4(u47, lb.z, u46) }
        for (int i = 0; i < 12; ++i) {
          int s = slot + (i << 4);
          if (s >= kp + 8) {
            int phys = rowmap[s];
            float4 la = As4[phys * 49 + pc];
            float4 lb = As4[phys * 49 + pc + 1];
            float4 c = As4[phys * 49 + q];
            FMA4(c, la.x, u40) FMA4(c, la.y, u41) FMA4(c, la.z, u42) FMA4(c, la.w, u43)
            FMA4(c, lb.x, u44) FMA4(c, lb.y, u45) FMA4(c, lb.z, u46) FMA4(c, lb.w, u47)
            As4[phys * 49 + q] = c;
          }
        }
      }
    }
    __syncthreads();  // trailing matrix ready for next panel
  }

  if (tid == 0) {
    float s = 0.f;
    for (int i = 0; i < 192; ++i) s += diagU[i];
    ssum[b] = s;
  }
  if (tid < 192) dvalf[tid] = ssign[tid] * expf(diagU[tid]) - diagU[tid];
  __syncthreads();
  {
    const int r = tid >> 2;
    const int tq = tid & 3;
    int i = r;
    int phys = rowmap[r];
    float di = dvalf[i];
    float* __restrict__ G = A + (size_t)phys * 192;   // output row = original row phys
    int qi = i >> 2;
    for (int j = 0; j < 12; ++j) {
      int q = tq + 4 * j;
      if (q > qi) continue;
      float4 g4 = *(float4*)(G + 4 * q);
      float4 a4 = As4[phys * 49 + q];
      float4 d4 = dval4[q];
      if (q == qi) {
        int c0 = 4 * q;
        g4.x = (c0 + 0 < i) ? g4.x + a4.x * d4.x : ((c0 + 0 == i) ? g4.x + di : g4.x);
        g4.y = (c0 + 1 < i) ? g4.y + a4.y * d4.y : ((c0 + 1 == i) ? g4.y + di : g4.y);
        g4.z = (c0 + 2 < i) ? g4.z + a4.z * d4.z : ((c0 + 2 == i) ? g4.z + di : g4.z);
        g4.w = (c0 + 3 < i) ? g4.w + a4.w * d4.w : ((c0 + 3 == i) ? g4.w + di : g4.w);
      } else {
        g4.x += a4.x * d4.x;
        g4.y += a4.y * d4.y;
        g4.z += a4.z * d4.z;
        g4.w += a4.w * d4.w;
      }
      *(float4*)(G + 4 * q) = g4;
    }
  }
}

// ---------------- Stage 5: out[b] = weight[b] @ inp[b]  (+ logdet write) ----------
__global__ __launch_bounds__(256) void out_kernel(const float* __restrict__ wt,
                                                  const float* __restrict__ inp,
                                                  const float* __restrict__ ssum,
                                                  float* __restrict__ out) {
  int blk = blockIdx.x;
  int b = blk / 24, rem = blk % 24;
  int it = rem >> 3, jt = rem & 7;
  int i0 = it << 6, hw0 = jt << 7;
  int tid = threadIdx.x;
  int tx = tid & 31, ty = tid >> 5;
  __shared__ float wlds[64 * 36];
  __shared__ float xlds[32 * 128];
  const float* wb = wt + (size_t)b * NN;
  const float* xb = inp + (((size_t)b * 192) << 10);
  float acc[8][4];
#pragma unroll
  for (int r = 0; r < 8; ++r)
#pragma unroll
    for (int c = 0; c < 4; ++c) acc[r][c] = 0.f;
  for (int kc = 0; kc < 6; ++kc) {
    __syncthreads();
#pragma unroll
    for (int j = 0; j < 2; ++j) {
      int f4 = tid + (j << 8);
      int row = f4 >> 3, c4 = (f4 & 7) << 2;
      float4 v = *(const float4*)(wb + (size_t)(i0 + row) * 192 + (kc << 5) + c4);
      *(float4*)(wlds + row * 36 + c4) = v;
    }
#pragma unroll
    for (int j = 0; j < 4; ++j) {
      int f4 = tid + (j << 8);
      int row = f4 >> 5, c4 = (f4 & 31) << 2;
      float4 v = *(const float4*)(xb + (((size_t)(kc << 5) + row) << 10) + hw0 + c4);
      *(float4*)(xlds + (row << 7) + c4) = v;
    }
    __syncthreads();
#pragma unroll 4
    for (int k = 0; k < 32; ++k) {
      float4 xv = *(const float4*)(xlds + (k << 7) + (tx << 2));
      float wr[8];
#pragma unroll
      for (int r = 0; r < 8; ++r) wr[r] = wlds[(ty * 8 + r) * 36 + k];
#pragma unroll
      for (int r = 0; r < 8; ++r) {
        acc[r][0] = fmaf(wr[r], xv.x, acc[r][0]);
        acc[r][1] = fmaf(wr[r], xv.y, acc[r][1]);
        acc[r][2] = fmaf(wr[r], xv.z, acc[r][2]);
        acc[r][3] = fmaf(wr[r], xv.w, acc[r][3]);
      }
    }
  }
  float* ob = out + (((size_t)b * 192 + i0 + ty * 8) << 10) + hw0 + (tx << 2);
#pragma unroll
  for (int r = 0; r < 8; ++r) {
    float4 v = make_float4(acc[r][0], acc[r][1], acc[r][2], acc[r][3]);
    *(float4*)(ob + ((size_t)r << 10)) = v;
  }
  if (blk == 0 && tid == 0) {
    float s = 0.f;
    for (int i = 0; i < 32; ++i) s += ssum[i];
    out[6291456] = 32.f * s;   // H*W * mean over batch of sum(s)
  }
}

extern "C" void kernel_launch(void* const* d_in, const int* in_sizes, int n_in,
                              void* d_out, int out_size, void* d_ws, size_t ws_size,
                              hipStream_t stream) {
  const float* inp = (const float*)d_in[0];
  const float* wlo = (const float*)d_in[1];
  const float* cw  = (const float*)d_in[2];
  const float* cb  = (const float*)d_in[3];
  const float* lw  = (const float*)d_in[4];
  const float* lb  = (const float*)d_in[5];
  const float* ss  = (const float*)d_in[6];
  float* out = (float*)d_out;
  float* ws = (float*)d_ws;
  // ws layout (floats): hpart 262144 | h_t 65536 | mats 1179648 | ssum 32  (~6 MB)
  float* hpart = ws;
  float* h_t   = ws + 262144;
  float* mats  = ws + 327680;
  float* ssum  = ws + 1507328;
  hipLaunchKernelGGL(conv_kernel,    dim3(128), dim3(256), 0, stream, wlo, cw, hpart);
  hipLaunchKernelGGL(hreduce_kernel, dim3(256), dim3(256), 0, stream, hpart, cb, h_t);
  hipLaunchKernelGGL(linear_kernel,  dim3(576), dim3(256), 0, stream, h_t, lw, lb, mats);
  hipLaunchKernelGGL(lu_kernel,      dim3(32),  dim3(768), 0, stream, mats, ss, ssum);
  hipLaunchKernelGGL(out_kernel,     dim3(768), dim3(256), 0, stream, mats, inp, ssum, out);
}

// Round 10
// 476.707 us; speedup vs baseline: 1.8479x; 1.0268x over previous
//
#include <hip/hip_runtime.h>
#include <math.h>

// Problem: B=32, C=192, H=W=32, CH=8, stride=2 -> FEAT=2048, N=C*C=36864
// Pipeline: conv(+relu) -> linear -> per-batch LU (partial pivot) ->
//           weight = mats + P*(L*diag(d)) in-place -> out = weight @ inp ; logdet.

#define NFEAT 2048
#define NN    36864

// ---------------- Stage 1: conv partials (c-sliced) ----------------
__global__ __launch_bounds__(256) void conv_kernel(const float* __restrict__ w,
                                                   const float* __restrict__ cw,
                                                   float* __restrict__ hpart) {
  int blk = blockIdx.x;
  int b = blk >> 2, cs = blk & 3;
  int tid = threadIdx.x;
  int oy = tid >> 4, ox = tid & 15;
  __shared__ float wlds[8 * 48 * 9];
  for (int idx = tid; idx < 8 * 48 * 9; idx += 256) {
    int ch = idx / 432, rem = idx - ch * 432;
    int c = rem / 9, kk = rem - c * 9;
    wlds[idx] = cw[ch * 1728 + (cs * 48 + c) * 9 + kk];
  }
  __syncthreads();
  float acc[8];
#pragma unroll
  for (int ch = 0; ch < 8; ++ch) acc[ch] = 0.f;
  const float* img0 = w + (((size_t)b * 192 + cs * 48) << 10);
  for (int c = 0; c < 48; ++c) {
    const float* img = img0 + ((size_t)c << 10);
    float iv[9];
#pragma unroll
    for (int ky = 0; ky < 3; ++ky)
#pragma unroll
      for (int kx = 0; kx < 3; ++kx) {
        int iy = 2 * oy - 1 + ky, ix = 2 * ox - 1 + kx;
        bool ok = (iy >= 0) & (iy < 32) & (ix >= 0) & (ix < 32);
        iv[ky * 3 + kx] = ok ? img[iy * 32 + ix] : 0.f;
      }
#pragma unroll
    for (int ch = 0; ch < 8; ++ch) {
      const float* wp = &wlds[(ch * 48 + c) * 9];
      float s = acc[ch];
#pragma unroll
      for (int t = 0; t < 9; ++t) s = fmaf(iv[t], wp[t], s);
      acc[ch] = s;
    }
  }
  size_t base = ((size_t)(cs * 32 + b) << 11) + tid;
#pragma unroll
  for (int ch = 0; ch < 8; ++ch) hpart[base + (ch << 8)] = acc[ch];
}

// ---------------- Stage 2: reduce partials + bias + relu -> h_t[k][b] --------------
__global__ __launch_bounds__(256) void hreduce_kernel(const float* __restrict__ hpart,
                                                      const float* __restrict__ cb,
                                                      float* __restrict__ h_t) {
  int g = blockIdx.x * 256 + threadIdx.x;   // 0..65535
  int k = g & 2047, b = g >> 11;
  float s = 0.f;
#pragma unroll
  for (int cs = 0; cs < 4; ++cs) s += hpart[(((size_t)(cs * 32 + b)) << 11) + k];
  s += cb[k >> 8];
  s = fmaxf(s, 0.f);
  h_t[((size_t)k << 5) + b] = s;
}

// ---------------- Stage 3: linear (R7 structure, bit-exact quarter sums) ------
__global__ __launch_bounds__(256) void linear_kernel(const float* __restrict__ h_t,
                                                     const float* __restrict__ lw,
                                                     const float* __restrict__ lb,
                                                     float* __restrict__ mats) {
  __shared__ float Wbuf[64 * 68];
  __shared__ float Hbuf[64 * 36];
  int tid = threadIdx.x;
  int n0 = blockIdx.x << 6;
  int half = tid >> 5;
  int bb = tid & 31;
  int nb = half << 3;
  float accq0[8], accq1[8], accq2[8], accq3[8];
#pragma unroll
  for (int j = 0; j < 8; ++j) { accq0[j] = 0.f; accq1[j] = 0.f; accq2[j] = 0.f; accq3[j] = 0.f; }

#define LIN_CHUNK(ACC)                                                         \
  {                                                                            \
    int koff = kc << 6;                                                        \
    _Pragma("unroll") for (int j = 0; j < 4; ++j) {                            \
      int f = tid + (j << 8);                                                  \
      int row = f >> 4, c4 = (f & 15) << 2;                                    \
      *(float4*)(Wbuf + row * 68 + c4) =                                       \
          *(const float4*)(lw + (size_t)(n0 + row) * 2048 + koff + c4);        \
    }                                                                          \
    _Pragma("unroll") for (int j = 0; j < 2; ++j) {                            \
      int f = tid + (j << 8);                                                  \
      int kr = f >> 3, b4 = (f & 7) << 2;                                      \
      *(float4*)(Hbuf + kr * 36 + b4) =                                        \
          *(const float4*)(h_t + (((size_t)(koff + kr)) << 5) + b4);           \
    }                                                                          \
    __syncthreads();                                                           \
    _Pragma("unroll 4") for (int k4 = 0; k4 < 16; ++k4) {                      \
      int kk = k4 << 2;                                                        \
      float h0 = Hbuf[(kk + 0) * 36 + bb];                                     \
      float h1 = Hbuf[(kk + 1) * 36 + bb];                                     \
      float h2 = Hbuf[(kk + 2) * 36 + bb];                                     \
      float h3 = Hbuf[(kk + 3) * 36 + bb];                                     \
      _Pragma("unroll") for (int j = 0; j < 8; ++j) {                          \
        float4 w4 = *(const float4*)(Wbuf + (nb + j) * 68 + kk);               \
        float s = ACC[j];                                                      \
        s = fmaf(w4.x, h0, s);                                                 \
        s = fmaf(w4.y, h1, s);                                                 \
        s = fmaf(w4.z, h2, s);                                                 \
        s = fmaf(w4.w, h3, s);                                                 \
        ACC[j] = s;                                                            \
      }                                                                        \
    }                                                                          \
    __syncthreads();                                                           \
  }

  for (int kc = 0; kc < 8; ++kc)  LIN_CHUNK(accq0)
  for (int kc = 8; kc < 16; ++kc) LIN_CHUNK(accq1)
  for (int kc = 16; kc < 24; ++kc) LIN_CHUNK(accq2)
  for (int kc = 24; kc < 32; ++kc) LIN_CHUNK(accq3)
#undef LIN_CHUNK

  float o[8];
#pragma unroll
  for (int j = 0; j < 8; ++j)
    o[j] = ((accq0[j] + accq1[j]) + accq2[j]) + accq3[j] + lb[n0 + nb + j];
  float* mp = mats + (size_t)bb * NN + n0 + nb;
  *(float4*)(mp + 0) = make_float4(o[0], o[1], o[2], o[3]);
  *(float4*)(mp + 4) = make_float4(o[4], o[5], o[6], o[7]);
}

// ---------------- Stage 4: BLOCKED LU with LOOKAHEAD (NB=8), LDS-resident ----------
// R8 post-mortem: design sound, ONE bug -- `rsl = tid & 383` is not mod-384
// (384 non-pow2): duplicate/missing phase-A rows -> racy double updates -> 1.7e16.
// R9 = R8 with rsl fixed via conditional subtract. Race ledger (re-audited):
// phaseB wave0 touches cols {qp1,qp1+1} + rowmap[>=kp+8] + diagU[kp+8..]; phaseB
// GEMM touches cols >= qp1+2, reads L cols {pc,pc+1}, u-rows rowmap[kp..kp+7]
// (stable), phys rows snapshotted pre-bar2 -- all disjoint. Arithmetic op-for-op
// identical to R6/R7 (absmax must equal 4194304).
#define CAT_(A, B) A##B
#define CAT(A, B) CAT_(A, B)
#define PR_0(R) CAT(pA, R).x
#define PR_1(R) CAT(pA, R).y
#define PR_2(R) CAT(pA, R).z
#define PR_3(R) CAT(pA, R).w
#define PR_4(R) CAT(pB, R).x
#define PR_5(R) CAT(pB, R).y
#define PR_6(R) CAT(pB, R).z
#define PR_7(R) CAT(pB, R).w
#define PR(R, K) CAT(PR_, K)(R)
#define UU_0 uA.x
#define UU_1 uA.y
#define UU_2 uA.z
#define UU_3 uA.w
#define UU_4 uB.x
#define UU_5 uB.y
#define UU_6 uB.z
#define UU_7 uB.w
#define UU(K) CAT(UU_, K)
#define UPDJ(R, J) PR(R, J) = fmaf(-m, UU(J), PR(R, J));
#define TAIL_0(R) UPDJ(R,1) UPDJ(R,2) UPDJ(R,3) UPDJ(R,4) UPDJ(R,5) UPDJ(R,6) UPDJ(R,7)
#define TAIL_1(R) UPDJ(R,2) UPDJ(R,3) UPDJ(R,4) UPDJ(R,5) UPDJ(R,6) UPDJ(R,7)
#define TAIL_2(R) UPDJ(R,3) UPDJ(R,4) UPDJ(R,5) UPDJ(R,6) UPDJ(R,7)
#define TAIL_3(R) UPDJ(R,4) UPDJ(R,5) UPDJ(R,6) UPDJ(R,7)
#define TAIL_4(R) UPDJ(R,5) UPDJ(R,6) UPDJ(R,7)
#define TAIL_5(R) UPDJ(R,6) UPDJ(R,7)
#define TAIL_6(R) UPDJ(R,7)
#define TAIL_7(R)
#define UPDROW(R, KK, kg)                                                      \
  if (CAT(lg, R) > (kg)) {                                                     \
    float m = PR(R, KK) * recip;                                               \
    PR(R, KK) = m;                                                             \
    CAT(TAIL_, KK)(R)                                                          \
  }
#define PSTEP(KK) {                                                            \
  const int kg = kpP + KK;                                                     \
  float bv = -1.f; int br = 0x7fffffff;                                        \
  { float v = fabsf(PR(0,KK)); if (lg0 >= kg && (v > bv || (v == bv && lg0 < br))) { bv = v; br = lg0; } } \
  { float v = fabsf(PR(1,KK)); if (lg1 >= kg && (v > bv || (v == bv && lg1 < br))) { bv = v; br = lg1; } } \
  { float v = fabsf(PR(2,KK)); if (lg2 >= kg && (v > bv || (v == bv && lg2 < br))) { bv = v; br = lg2; } } \
  for (int msk = 1; msk <= 32; msk <<= 1) {                                    \
    float ov = __shfl_xor(bv, msk, 64);                                        \
    int obr = __shfl_xor(br, msk, 64);                                         \
    if (ov > bv || (ov == bv && obr < br)) { bv = ov; br = obr; }              \
  }                                                                            \
  bool own0 = (lg0 == br), own1 = (lg1 == br), own2 = (lg2 == br);             \
  float4 sA = own1 ? pA1 : (own2 ? pA2 : pA0);                                 \
  float4 sB = own1 ? pB1 : (own2 ? pB2 : pB0);                                 \
  int owner = (int)__ffsll(__ballot(own0 | own1 | own2)) - 1;                  \
  float4 uA, uB;                                                               \
  uA.x = __shfl(sA.x, owner); uA.y = __shfl(sA.y, owner);                      \
  uA.z = __shfl(sA.z, owner); uA.w = __shfl(sA.w, owner);                      \
  uB.x = __shfl(sB.x, owner); uB.y = __shfl(sB.y, owner);                      \
  uB.z = __shfl(sB.z, owner); uB.w = __shfl(sB.w, owner);                      \
  float piv = UU(KK);                                                          \
  float recip = 1.0f / piv;                                                    \
  if (tid == 0) {                                                              \
    diagU[kg] = piv;                                                           \
    int t0 = rowmap[kg], t1 = rowmap[br];                                      \
    rowmap[kg] = t1; rowmap[br] = t0;                                          \
  }                                                                            \
  lg0 = (lg0 == kg) ? br : ((lg0 == br) ? kg : lg0);                           \
  lg1 = (lg1 == kg) ? br : ((lg1 == br) ? kg : lg1);                           \
  lg2 = (lg2 == kg) ? br : ((lg2 == br) ? kg : lg2);                           \
  UPDROW(0, KK, kg)                                                            \
  UPDROW(1, KK, kg)                                                            \
  UPDROW(2, KK, kg)                                                            \
}
#define FMA4(D, M, S) {                                                        \
  float mm = (M);                                                              \
  D.x = fmaf(-mm, S.x, D.x); D.y = fmaf(-mm, S.y, D.y);                        \
  D.z = fmaf(-mm, S.z, D.z); D.w = fmaf(-mm, S.w, D.w);                        \
}
// panel factorization of cols [KPV, KPV+8), wave 0 only, all in registers
#define PANEL(KPV) {                                                           \
  const int kpP = (KPV);                                                       \
  const int pcP = kpP >> 2;                                                    \
  float4 pA0 = As4[tid * 49 + pcP],         pB0 = As4[tid * 49 + pcP + 1];     \
  float4 pA1 = As4[(tid + 64) * 49 + pcP],  pB1 = As4[(tid + 64) * 49 + pcP + 1]; \
  float4 pA2 = As4[(tid + 128) * 49 + pcP], pB2 = As4[(tid + 128) * 49 + pcP + 1]; \
  PSTEP(0) PSTEP(1) PSTEP(2) PSTEP(3) PSTEP(4) PSTEP(5) PSTEP(6) PSTEP(7)     \
  As4[tid * 49 + pcP] = pA0;         As4[tid * 49 + pcP + 1] = pB0;            \
  As4[(tid + 64) * 49 + pcP] = pA1;  As4[(tid + 64) * 49 + pcP + 1] = pB1;     \
  As4[(tid + 128) * 49 + pcP] = pA2; As4[(tid + 128) * 49 + pcP + 1] = pB2;    \
}

__global__ __launch_bounds__(768, 1) void lu_kernel(float* __restrict__ A0,
                                                    const float* __restrict__ ssign,
                                                    float* __restrict__ ssum) {
  __shared__ float4 As4[192 * 49];     // 150528 B, row stride 49 float4
  __shared__ int rowmap[192];
  __shared__ float diagU[192];
  __shared__ float4 dval4[48];
  float* dvalf = (float*)dval4;
  int b = blockIdx.x;
  int tid = threadIdx.x;
  float* __restrict__ A = A0 + (size_t)b * NN;

#pragma unroll
  for (int j = 0; j < 12; ++j) {
    int chunk = tid + 768 * j;
    int row = chunk / 48, q = chunk - row * 48;
    As4[row * 49 + q] = *(const float4*)(A + row * 192 + 4 * q);
  }
  for (int i = tid; i < 192; i += 768) rowmap[i] = i;
  __syncthreads();

  int lg0 = tid, lg1 = tid + 64, lg2 = tid + 128;   // logical pos of wave0's rows

  // prologue: factorize panel 0
  if (tid < 64) { PANEL(0) }
  __syncthreads();

  const int qg = tid >> 4;       // phaseB GEMM chunk column
  const int slot = tid & 15;

  for (int p = 0; p < 23; ++p) {
    const int kp = p << 3;
    const int pc = kp >> 2;
    const int qp1 = pc + 2;      // first trailing chunk (= next panel's cols)

    // ---- phase 1: TRSM once per chunk column q in [qp1,48), store U rows ----
    if (tid >= qp1 && tid < 48) {
      const int q = tid;
      const int ur0 = rowmap[kp + 0], ur1 = rowmap[kp + 1];
      const int ur2 = rowmap[kp + 2], ur3 = rowmap[kp + 3];
      const int ur4 = rowmap[kp + 4], ur5 = rowmap[kp + 5];
      const int ur6 = rowmap[kp + 6], ur7 = rowmap[kp + 7];
      float4 u40 = As4[ur0 * 49 + q], u41 = As4[ur1 * 49 + q];
      float4 u42 = As4[ur2 * 49 + q], u43 = As4[ur3 * 49 + q];
      float4 u44 = As4[ur4 * 49 + q], u45 = As4[ur5 * 49 + q];
      float4 u46 = As4[ur6 * 49 + q], u47 = As4[ur7 * 49 + q];
      { float4 la = As4[ur1 * 49 + pc];
        FMA4(u41, la.x, u40) }
      { float4 la = As4[ur2 * 49 + pc];
        FMA4(u42, la.x, u40) FMA4(u42, la.y, u41) }
      { float4 la = As4[ur3 * 49 + pc];
        FMA4(u43, la.x, u40) FMA4(u43, la.y, u41) FMA4(u43, la.z, u42) }
      { float4 la = As4[ur4 * 49 + pc];
        FMA4(u44, la.x, u40) FMA4(u44, la.y, u41) FMA4(u44, la.z, u42) FMA4(u44, la.w, u43) }
      { float4 la = As4[ur5 * 49 + pc]; float4 lb2 = As4[ur5 * 49 + pc + 1];
        FMA4(u45, la.x, u40) FMA4(u45, la.y, u41) FMA4(u45, la.z, u42) FMA4(u45, la.w, u43)
        FMA4(u45, lb2.x, u44) }
      { float4 la = As4[ur6 * 49 + pc]; float4 lb2 = As4[ur6 * 49 + pc + 1];
        FMA4(u46, la.x, u40) FMA4(u46, la.y, u41) FMA4(u46, la.z, u42) FMA4(u46, la.w, u43)
        FMA4(u46, lb2.x, u44) FMA4(u46, lb2.y, u45) }
      { float4 la = As4[ur7 * 49 + pc]; float4 lb2 = As4[ur7 * 49 + pc + 1];
        FMA4(u47, la.x, u40) FMA4(u47, la.y, u41) FMA4(u47, la.z, u42) FMA4(u47, la.w, u43)
        FMA4(u47, lb2.x, u44) FMA4(u47, lb2.y, u45) FMA4(u47, lb2.z, u46) }
      As4[ur0 * 49 + q] = u40; As4[ur1 * 49 + q] = u41;
      As4[ur2 * 49 + q] = u42; As4[ur3 * 49 + q] = u43;
      As4[ur4 * 49 + q] = u44; As4[ur5 * 49 + q] = u45;
      As4[ur6 * 49 + q] = u46; As4[ur7 * 49 + q] = u47;
    }
    __syncthreads();  // bar1: TRSM'd U visible

    // ---- phase A: GEMM the next panel's 2 chunk cols + snapshot phys regs ----
    {
      const int col = qp1 + (tid >= 384 ? 1 : 0);
      const int rsl = tid - (tid >= 384 ? 384 : 0);   // R8 bug: was tid&383 (384 non-pow2)
      const int s = kp + 8 + rsl;
      if (s < 192) {
        const int ua0 = rowmap[kp + 0], ua1 = rowmap[kp + 1];
        const int ua2 = rowmap[kp + 2], ua3 = rowmap[kp + 3];
        const int ua4 = rowmap[kp + 4], ua5 = rowmap[kp + 5];
        const int ua6 = rowmap[kp + 6], ua7 = rowmap[kp + 7];
        float4 u40 = As4[ua0 * 49 + col], u41 = As4[ua1 * 49 + col];
        float4 u42 = As4[ua2 * 49 + col], u43 = As4[ua3 * 49 + col];
        float4 u44 = As4[ua4 * 49 + col], u45 = As4[ua5 * 49 + col];
        float4 u46 = As4[ua6 * 49 + col], u47 = As4[ua7 * 49 + col];
        int phys = rowmap[s];
        float4 la = As4[phys * 49 + pc];
        float4 lb2 = As4[phys * 49 + pc + 1];
        float4 c = As4[phys * 49 + col];
        FMA4(c, la.x, u40) FMA4(c, la.y, u41) FMA4(c, la.z, u42) FMA4(c, la.w, u43)
        FMA4(c, lb2.x, u44) FMA4(c, lb2.y, u45) FMA4(c, lb2.z, u46) FMA4(c, lb2.w, u47)
        As4[phys * 49 + col] = c;
      }
    }
    // snapshot phys rows for phase B (named regs; rowmap stable until bar2)
    int php0, php1, php2, php3, php4, php5, php6, php7, php8, php9, php10, php11;
#define SNAP(I) CAT(php, I) = rowmap[slot + (I << 4)];
    SNAP(0) SNAP(1) SNAP(2) SNAP(3) SNAP(4) SNAP(5) SNAP(6)
    SNAP(7) SNAP(8) SNAP(9) SNAP(10) SNAP(11)
#undef SNAP
    __syncthreads();  // bar2: next-panel cols ready; snapshots taken

    // ---- phase B: wave0 factorizes panel p+1 || others GEMM cols >= qp1+2 ----
    if (tid < 64) {
      PANEL(kp + 8)
    } else if (qg >= qp1 + 2) {
      const int q = qg;
      const int ub0 = rowmap[kp + 0], ub1 = rowmap[kp + 1];
      const int ub2 = rowmap[kp + 2], ub3 = rowmap[kp + 3];
      const int ub4 = rowmap[kp + 4], ub5 = rowmap[kp + 5];
      const int ub6 = rowmap[kp + 6], ub7 = rowmap[kp + 7];
      float4 u40 = As4[ub0 * 49 + q], u41 = As4[ub1 * 49 + q];
      float4 u42 = As4[ub2 * 49 + q], u43 = As4[ub3 * 49 + q];
      float4 u44 = As4[ub4 * 49 + q], u45 = As4[ub5 * 49 + q];
      float4 u46 = As4[ub6 * 49 + q], u47 = As4[ub7 * 49 + q];
#define GEMMROW(I) {                                                           \
      int s = slot + (I << 4);                                                 \
      if (s >= kp + 8) {                                                       \
        int phys = CAT(php, I);                                                \
        float4 la = As4[phys * 49 + pc];                                       \
        float4 lb2 = As4[phys * 49 + pc + 1];                                  \
        float4 c = As4[phys * 49 + q];                                         \
        FMA4(c, la.x, u40) FMA4(c, la.y, u41) FMA4(c, la.z, u42) FMA4(c, la.w, u43) \
        FMA4(c, lb2.x, u44) FMA4(c, lb2.y, u45) FMA4(c, lb2.z, u46) FMA4(c, lb2.w, u47) \
        As4[phys * 49 + q] = c;                                                \
      }                                                                        \
    }
      GEMMROW(0) GEMMROW(1) GEMMROW(2) GEMMROW(3) GEMMROW(4) GEMMROW(5)
      GEMMROW(6) GEMMROW(7) GEMMROW(8) GEMMROW(9) GEMMROW(10) GEMMROW(11)
#undef GEMMROW
    }
    __syncthreads();  // bar3: panel p+1 factorized; trailing(p) complete
  }

  // ---- epilogue: logdet partial, dval, weight = mats + P*(L*diag(d)) ----
  if (tid == 0) {
    float s = 0.f;
    for (int i = 0; i < 192; ++i) s += diagU[i];
    ssum[b] = s;
  }
  if (tid < 192) dvalf[tid] = ssign[tid] * expf(diagU[tid]) - diagU[tid];
  __syncthreads();
  {
    const int r = tid >> 2;
    const int tq = tid & 3;
    int i = r;
    int phys = rowmap[r];
    float di = dvalf[i];
    float* __restrict__ G = A + (size_t)phys * 192;   // output row = original row phys
    int qi = i >> 2;
    for (int j = 0; j < 12; ++j) {
      int q = tq + 4 * j;
      if (q > qi) continue;
      float4 g4 = *(float4*)(G + 4 * q);
      float4 a4 = As4[phys * 49 + q];
      float4 d4 = dval4[q];
      if (q == qi) {
        int c0 = 4 * q;
        g4.x = (c0 + 0 < i) ? g4.x + a4.x * d4.x : ((c0 + 0 == i) ? g4.x + di : g4.x);
        g4.y = (c0 + 1 < i) ? g4.y + a4.y * d4.y : ((c0 + 1 == i) ? g4.y + di : g4.y);
        g4.z = (c0 + 2 < i) ? g4.z + a4.z * d4.z : ((c0 + 2 == i) ? g4.z + di : g4.z);
        g4.w = (c0 + 3 < i) ? g4.w + a4.w * d4.w : ((c0 + 3 == i) ? g4.w + di : g4.w);
      } else {
        g4.x += a4.x * d4.x;
        g4.y += a4.y * d4.y;
        g4.z += a4.z * d4.z;
        g4.w += a4.w * d4.w;
      }
      *(float4*)(G + 4 * q) = g4;
    }
  }
}

// ---------------- Stage 5: out[b] = weight[b] @ inp[b]  (+ logdet write) ----------
__global__ __launch_bounds__(256) void out_kernel(const float* __restrict__ wt,
                                                  const float* __restrict__ inp,
                                                  const float* __restrict__ ssum,
                                                  float* __restrict__ out) {
  int blk = blockIdx.x;
  int b = blk / 24, rem = blk % 24;
  int it = rem >> 3, jt = rem & 7;
  int i0 = it << 6, hw0 = jt << 7;
  int tid = threadIdx.x;
  int tx = tid & 31, ty = tid >> 5;
  __shared__ float wlds[64 * 36];
  __shared__ float xlds[32 * 128];
  const float* wb = wt + (size_t)b * NN;
  const float* xb = inp + (((size_t)b * 192) << 10);
  float acc[8][4];
#pragma unroll
  for (int r = 0; r < 8; ++r)
#pragma unroll
    for (int c = 0; c < 4; ++c) acc[r][c] = 0.f;
  for (int kc = 0; kc < 6; ++kc) {
    __syncthreads();
#pragma unroll
    for (int j = 0; j < 2; ++j) {
      int f4 = tid + (j << 8);
      int row = f4 >> 3, c4 = (f4 & 7) << 2;
      float4 v = *(const float4*)(wb + (size_t)(i0 + row) * 192 + (kc << 5) + c4);
      *(float4*)(wlds + row * 36 + c4) = v;
    }
#pragma unroll
    for (int j = 0; j < 4; ++j) {
      int f4 = tid + (j << 8);
      int row = f4 >> 5, c4 = (f4 & 31) << 2;
      float4 v = *(const float4*)(xb + (((size_t)(kc << 5) + row) << 10) + hw0 + c4);
      *(float4*)(xlds + (row << 7) + c4) = v;
    }
    __syncthreads();
#pragma unroll 4
    for (int k = 0; k < 32; ++k) {
      float4 xv = *(const float4*)(xlds + (k << 7) + (tx << 2));
      float wr[8];
#pragma unroll
      for (int r = 0; r < 8; ++r) wr[r] = wlds[(ty * 8 + r) * 36 + k];
#pragma unroll
      for (int r = 0; r < 8; ++r) {
        acc[r][0] = fmaf(wr[r], xv.x, acc[r][0]);
        acc[r][1] = fmaf(wr[r], xv.y, acc[r][1]);
        acc[r][2] = fmaf(wr[r], xv.z, acc[r][2]);
        acc[r][3] = fmaf(wr[r], xv.w, acc[r][3]);
      }
    }
  }
  float* ob = out + (((size_t)b * 192 + i0 + ty * 8) << 10) + hw0 + (tx << 2);
#pragma unroll
  for (int r = 0; r < 8; ++r) {
    float4 v = make_float4(acc[r][0], acc[r][1], acc[r][2], acc[r][3]);
    *(float4*)(ob + ((size_t)r << 10)) = v;
  }
  if (blk == 0 && tid == 0) {
    float s = 0.f;
    for (int i = 0; i < 32; ++i) s += ssum[i];
    out[6291456] = 32.f * s;   // H*W * mean over batch of sum(s)
  }
}

extern "C" void kernel_launch(void* const* d_in, const int* in_sizes, int n_in,
                              void* d_out, int out_size, void* d_ws, size_t ws_size,
                              hipStream_t stream) {
  const float* inp = (const float*)d_in[0];
  const float* wlo = (const float*)d_in[1];
  const float* cw  = (const float*)d_in[2];
  const float* cb  = (const float*)d_in[3];
  const float* lw  = (const float*)d_in[4];
  const float* lb  = (const float*)d_in[5];
  const float* ss  = (const float*)d_in[6];
  float* out = (float*)d_out;
  float* ws = (float*)d_ws;
  // ws layout (floats): hpart 262144 | h_t 65536 | mats 1179648 | ssum 32  (~6 MB)
  float* hpart = ws;
  float* h_t   = ws + 262144;
  float* mats  = ws + 327680;
  float* ssum  = ws + 1507328;
  hipLaunchKernelGGL(conv_kernel,    dim3(128), dim3(256), 0, stream, wlo, cw, hpart);
  hipLaunchKernelGGL(hreduce_kernel, dim3(256), dim3(256), 0, stream, hpart, cb, h_t);
  hipLaunchKernelGGL(linear_kernel,  dim3(576), dim3(256), 0, stream, h_t, lw, lb, mats);
  hipLaunchKernelGGL(lu_kernel,      dim3(32),  dim3(768), 0, stream, mats, ss, ssum);
  hipLaunchKernelGGL(out_kernel,     dim3(768), dim3(256), 0, stream, mats, inp, ssum, out);
}